// Round 3
// baseline (8349.609 us; speedup 1.0000x reference)
//
#include <hip/hip_runtime.h>
#include <math.h>

typedef unsigned short u16;

#define NN 20000
#define PP 3
#define TLP 10
#define TNS 20
#define DD 128
#define EE 640000

__device__ __forceinline__ float bf2f(u16 u) {
  union { unsigned u; float f; } v; v.u = ((unsigned)u) << 16; return v.f;
}
__device__ __forceinline__ u16 f2bf(float f) {
  union { float f; unsigned u; } v; v.f = f;
  unsigned r = v.u + 0x7fffu + ((v.u >> 16) & 1u);
  return (u16)(r >> 16);
}
__device__ __forceinline__ float sigmf(float x) { return 1.f / (1.f + __expf(-x)); }
__device__ __forceinline__ float loadf(const void* p, size_t i, int isf) {
  return isf ? ((const float*)p)[i] : bf2f(((const u16*)p)[i]);
}

// ------------------------------------------------------------- dtype detect
// If the float inputs are really f32, the low half-word of each f32 contains
// mantissa bits; decoded as bf16 its exponent field is ~uniform -> huge values
// appear with P~0.38/sample. True bf16 embeddings (scale 0.5) never reach 2^32.
__global__ void k_detect(const void* probe, int* flag) {
  __shared__ int any;
  if (threadIdx.x == 0) any = 0;
  __syncthreads();
  const u16* p = (const u16*)probe;
  int bad = 0;
  for (int i = threadIdx.x; i < 4096; i += 256) {
    int e = (p[2 * i] >> 7) & 0xFF;
    if (e >= 0x9F) bad = 1;
  }
  if (bad) atomicOr(&any, 1);
  __syncthreads();
  if (threadIdx.x == 0) flag[0] = any;  // 1 = f32, 0 = bf16
}

// ------------------------------------------------------------- converters
struct CvtJobs {
  const void* src[24];
  int off[24];
  int n[24];
};

__global__ void k_cvt_batch(CvtJobs jobs, float* dst, const int* flag) {
  const int isf = flag[0];
  const void* s = jobs.src[blockIdx.x];
  float* d = dst + jobs.off[blockIdx.x];
  const int n = jobs.n[blockIdx.x];
  for (int i = threadIdx.x; i < n; i += 256) d[i] = loadf(s, i, isf);
}

// W: [R x C] row-major (raw dtype) -> WT: [C x R] f32 (k-major)
__global__ void k_cvt_transpose(const void* W, float* __restrict__ WT,
                                int R, int C, const int* flag) {
  const int isf = flag[0];
  int i = blockIdx.x * 256 + threadIdx.x;
  if (i >= R * C) return;
  int r = i / C, c = i - r * C;
  WT[(size_t)c * R + r] = loadf(W, i, isf);
}

// ---------------------------------------------------------------- GRU
// Persistent-H GRU: 32 sequences per block, 256 threads, all-f32 math.
// Thread (ty,tx): rows s0=2*ty.., cols d0=8*tx (2x8 register tile).
__global__ __launch_bounds__(256) void k_gru(
    const void* __restrict__ emb,    // [V, 128] raw dtype
    const int* __restrict__ idx,     // [rows, T]
    const int* __restrict__ lens,    // [rows]
    const float* __restrict__ WihT,  // [128, 384] f32, k-major
    const float* __restrict__ WhhT,  // [128, 384]
    const float* __restrict__ bih,   // [384] f32
    const float* __restrict__ bhh,   // [384]
    float* __restrict__ Hout,        // [numSeq, 128] f32
    int numSeq, int T, int mode, int Nn, const int* flag) {
  __shared__ float Xs[DD][33];
  __shared__ float Hs[DD][33];
  __shared__ float Bt[32][DD + 4];
  __shared__ int rowb[32];
  __shared__ int lenv[32];

  const int isf = flag[0];
  const int tid = threadIdx.x;
  const int ty = tid >> 4, tx = tid & 15;
  const int s0 = ty * 2, d0 = tx * 8;

  if (tid < 32) {
    int sg = blockIdx.x * 32 + tid;
    if (sg >= numSeq) sg = numSeq - 1;
    int row;
    if (mode == 0) { int p = sg / Nn; int i = sg - p * Nn; row = i * PP + p; }
    else row = sg;
    rowb[tid] = row * T;
    lenv[tid] = lens[row];
  }
  for (int z = tid; z < DD * 32; z += 256) Hs[z >> 5][z & 31] = 0.f;
  __syncthreads();

  float rr[2][8], zz[2][8];

  for (int t = 0; t < T; ++t) {
    {  // gather X_t -> Xs transposed
      int sl = tid >> 3;
      int k0 = (tid & 7) << 4;
      int iv = idx[rowb[sl] + t];
      if (isf) {
        const float* er = (const float*)emb + (size_t)iv * DD + k0;
#pragma unroll
        for (int q = 0; q < 4; ++q) {
          float4 v = *(const float4*)(er + 4 * q);
          Xs[k0 + 4 * q + 0][sl] = v.x; Xs[k0 + 4 * q + 1][sl] = v.y;
          Xs[k0 + 4 * q + 2][sl] = v.z; Xs[k0 + 4 * q + 3][sl] = v.w;
        }
      } else {
        const u16* er = (const u16*)emb + (size_t)iv * DD + k0;
#pragma unroll
        for (int k = 0; k < 16; ++k) Xs[k0 + k][sl] = bf2f(er[k]);
      }
    }
    __syncthreads();

    for (int g = 0; g < 3; ++g) {
      float accx[2][8], acch[2][8];
#pragma unroll
      for (int m = 0; m < 2; ++m)
#pragma unroll
        for (int n = 0; n < 8; ++n) { accx[m][n] = 0.f; acch[m][n] = 0.f; }

      for (int c = 0; c < 8; ++c) {  // 0..3 = X·Wih, 4..7 = H·Whh
        {
          int kk = tid >> 3;
          int dof = (tid & 7) << 4;
          int kloc = (c & 3) * 32 + kk;
          const float* src = ((c < 4) ? WihT : WhhT) + (size_t)kloc * 384 + g * DD + dof;
#pragma unroll
          for (int q = 0; q < 4; ++q) {
            float4 v = *(const float4*)(src + q * 4);
            Bt[kk][dof + q * 4 + 0] = v.x;
            Bt[kk][dof + q * 4 + 1] = v.y;
            Bt[kk][dof + q * 4 + 2] = v.z;
            Bt[kk][dof + q * 4 + 3] = v.w;
          }
        }
        __syncthreads();
        const int kbase = (c & 3) * 32;
        const int hsel = (c >= 4);
#pragma unroll
        for (int kk = 0; kk < 32; ++kk) {
          float a0 = hsel ? Hs[kbase + kk][s0] : Xs[kbase + kk][s0];
          float a1 = hsel ? Hs[kbase + kk][s0 + 1] : Xs[kbase + kk][s0 + 1];
          float4 b0 = *(const float4*)&Bt[kk][d0];
          float4 b1 = *(const float4*)&Bt[kk][d0 + 4];
          float bv[8] = {b0.x, b0.y, b0.z, b0.w, b1.x, b1.y, b1.z, b1.w};
          if (!hsel) {
#pragma unroll
            for (int n = 0; n < 8; ++n) {
              accx[0][n] += a0 * bv[n];
              accx[1][n] += a1 * bv[n];
            }
          } else {
#pragma unroll
            for (int n = 0; n < 8; ++n) {
              acch[0][n] += a0 * bv[n];
              acch[1][n] += a1 * bv[n];
            }
          }
        }
        __syncthreads();
      }

      if (g == 0) {
#pragma unroll
        for (int n = 0; n < 8; ++n) {
          float bsum = bih[d0 + n] + bhh[d0 + n];
#pragma unroll
          for (int m = 0; m < 2; ++m)
            rr[m][n] = sigmf(accx[m][n] + acch[m][n] + bsum);
        }
      } else if (g == 1) {
#pragma unroll
        for (int n = 0; n < 8; ++n) {
          float bsum = bih[DD + d0 + n] + bhh[DD + d0 + n];
#pragma unroll
          for (int m = 0; m < 2; ++m)
            zz[m][n] = sigmf(accx[m][n] + acch[m][n] + bsum);
        }
      } else {
#pragma unroll
        for (int n = 0; n < 8; ++n) {
          float bx = bih[2 * DD + d0 + n];
          float bh = bhh[2 * DD + d0 + n];
#pragma unroll
          for (int m = 0; m < 2; ++m) {
            float hold = Hs[d0 + n][s0 + m];
            float nn_ = tanhf(accx[m][n] + bx + rr[m][n] * (acch[m][n] + bh));
            float hnew = (1.f - zz[m][n]) * nn_ + zz[m][n] * hold;
            if (t < lenv[s0 + m]) Hs[d0 + n][s0 + m] = hnew;  // pack_padded mask
          }
        }
      }
    }
    __syncthreads();
  }

  int sgb = blockIdx.x * 32;
#pragma unroll
  for (int m = 0; m < 2; ++m) {
    int sg = sgb + s0 + m;
    if (sg < numSeq) {
      float4 o0 = make_float4(Hs[d0 + 0][s0 + m], Hs[d0 + 1][s0 + m],
                              Hs[d0 + 2][s0 + m], Hs[d0 + 3][s0 + m]);
      float4 o1 = make_float4(Hs[d0 + 4][s0 + m], Hs[d0 + 5][s0 + m],
                              Hs[d0 + 6][s0 + m], Hs[d0 + 7][s0 + m]);
      float4* dst = (float4*)(Hout + (size_t)sg * DD + d0);
      dst[0] = o0; dst[1] = o1;
    }
  }
}

// ---------------------------------------------------------------- GEMM
// C[M x 128] f32 = A[M x K] @ W[128 x K].T + bias (W, bias f32 pre-converted).
// mode 0: A flat f32, row stride K.
// mode 1: faithful scramble over stack [5N,128]: row i, k-block kb ->
//         stack row r5 = 5i+kb; slot = r5/NN; slots 0-2 raw dtype, 3-4 f32.
__global__ __launch_bounds__(256) void k_gemm(
    const float* __restrict__ A, const void* __restrict__ R0,
    const void* __restrict__ R1, const void* __restrict__ R2,
    const float* __restrict__ A3, const float* __restrict__ A4,
    int mode, int K, const float* __restrict__ W,
    const float* __restrict__ bias, float* __restrict__ C, const int* flag) {
  __shared__ float As[32][33];
  __shared__ float Bt[32][DD + 4];
  const int isf = flag[0];
  const int tid = threadIdx.x;
  const int ty = tid >> 4, tx = tid & 15;
  const int s0 = ty * 2, d0 = tx * 8;
  const int rbase = blockIdx.x * 32;
  const int sl = tid >> 3, ko4 = (tid & 7) << 2;
  const int dW = tid >> 1, koW = (tid & 1) << 4;

  float acc[2][8];
#pragma unroll
  for (int m = 0; m < 2; ++m)
#pragma unroll
    for (int n = 0; n < 8; ++n) acc[m][n] = 0.f;

  for (int k0 = 0; k0 < K; k0 += 32) {
    {
      float v0, v1, v2, v3;
      if (mode == 0) {
        float4 v = *(const float4*)(A + (size_t)(rbase + sl) * K + k0 + ko4);
        v0 = v.x; v1 = v.y; v2 = v.z; v3 = v.w;
      } else {
        int r5 = 5 * (rbase + sl) + (k0 >> 7);
        int slot = r5 / NN;
        int inner = r5 - slot * NN;
        size_t base = (size_t)inner * DD + (k0 & 127) + ko4;
        if (slot < 3) {
          const void* p = (slot == 0) ? R0 : (slot == 1) ? R1 : R2;
          v0 = loadf(p, base + 0, isf); v1 = loadf(p, base + 1, isf);
          v2 = loadf(p, base + 2, isf); v3 = loadf(p, base + 3, isf);
        } else {
          const float* p = (slot == 3) ? A3 : A4;
          float4 v = *(const float4*)(p + base);
          v0 = v.x; v1 = v.y; v2 = v.z; v3 = v.w;
        }
      }
      As[ko4 + 0][sl] = v0; As[ko4 + 1][sl] = v1;
      As[ko4 + 2][sl] = v2; As[ko4 + 3][sl] = v3;
    }
    {
      const float* srcw = W + (size_t)dW * K + k0 + koW;
#pragma unroll
      for (int q = 0; q < 4; ++q) {
        float4 v = *(const float4*)(srcw + q * 4);
        Bt[koW + q * 4 + 0][dW] = v.x;
        Bt[koW + q * 4 + 1][dW] = v.y;
        Bt[koW + q * 4 + 2][dW] = v.z;
        Bt[koW + q * 4 + 3][dW] = v.w;
      }
    }
    __syncthreads();
#pragma unroll
    for (int kk = 0; kk < 32; ++kk) {
      float a0 = As[kk][s0];
      float a1 = As[kk][s0 + 1];
      float4 b0 = *(const float4*)&Bt[kk][d0];
      float4 b1 = *(const float4*)&Bt[kk][d0 + 4];
      float bv[8] = {b0.x, b0.y, b0.z, b0.w, b1.x, b1.y, b1.z, b1.w};
#pragma unroll
      for (int n = 0; n < 8; ++n) {
        acc[0][n] += a0 * bv[n];
        acc[1][n] += a1 * bv[n];
      }
    }
    __syncthreads();
  }
#pragma unroll
  for (int m = 0; m < 2; ++m) {
    int r = rbase + s0 + m;
    float b0 = bias ? bias[d0 + 0] : 0.f, b1 = bias ? bias[d0 + 1] : 0.f;
    float b2 = bias ? bias[d0 + 2] : 0.f, b3 = bias ? bias[d0 + 3] : 0.f;
    float b4 = bias ? bias[d0 + 4] : 0.f, b5 = bias ? bias[d0 + 5] : 0.f;
    float b6 = bias ? bias[d0 + 6] : 0.f, b7 = bias ? bias[d0 + 7] : 0.f;
    float4* dst = (float4*)(C + (size_t)r * DD + d0);
    dst[0] = make_float4(acc[m][0] + b0, acc[m][1] + b1, acc[m][2] + b2, acc[m][3] + b3);
    dst[1] = make_float4(acc[m][4] + b4, acc[m][5] + b5, acc[m][6] + b6, acc[m][7] + b7);
  }
}

// ---------------------------------------------------------------- small kernels
__global__ void k_deg_init(float* __restrict__ deg, int n) {
  int i = blockIdx.x * 256 + threadIdx.x;
  if (i < n) deg[i] = 1.f;  // self-loop weight
}

__global__ void k_deg_acc(const int* __restrict__ dst, const void* __restrict__ w,
                          float* __restrict__ deg, int E, const int* flag) {
  const int isf = flag[0];
  int e = blockIdx.x * 256 + threadIdx.x;
  if (e < E) atomicAdd(&deg[dst[e]], loadf(w, e, isf));
}

__global__ void k_dinv(const float* __restrict__ deg, float* __restrict__ dinv, int n) {
  int i = blockIdx.x * 256 + threadIdx.x;
  if (i < n) dinv[i] = 1.f / sqrtf(deg[i]);  // deg >= 1 always
}

__global__ void k_gcn_self(const float* __restrict__ xw, const float* __restrict__ dinv,
                           const float* __restrict__ bias, float* __restrict__ out,
                           int total) {
  int i = blockIdx.x * 256 + threadIdx.x;
  if (i >= total) return;
  int r = i >> 7, d = i & 127;
  float di = dinv[r];
  out[i] = bias[d] + di * di * xw[i];
}

__global__ __launch_bounds__(256) void k_gcn_edges(
    const int* __restrict__ src, const int* __restrict__ dst,
    const void* __restrict__ w, const float* __restrict__ dinv,
    const float* __restrict__ xw, float* __restrict__ out, int E, const int* flag) {
  const int isf = flag[0];
  int e = blockIdx.x * 2 + (threadIdx.x >> 7);
  int d = threadIdx.x & 127;
  if (e >= E) return;
  int s = src[e], t = dst[e];
  float coef = dinv[s] * loadf(w, e, isf) * dinv[t];
  atomicAdd(&out[(size_t)t * DD + d], coef * xw[(size_t)s * DD + d]);
}

__global__ __launch_bounds__(256) void k_relu_ln(
    const float* __restrict__ in, const float* __restrict__ g,
    const float* __restrict__ b, float* __restrict__ out, int nrows) {
  int wid = (blockIdx.x * 256 + threadIdx.x) >> 6;
  int lane = threadIdx.x & 63;
  if (wid >= nrows) return;
  const float* row = in + (size_t)wid * DD;
  float x0 = fmaxf(row[lane], 0.f), x1 = fmaxf(row[lane + 64], 0.f);
  float s = x0 + x1;
#pragma unroll
  for (int off = 32; off; off >>= 1) s += __shfl_xor(s, off);
  float mean = s * (1.f / 128.f);
  float e0 = x0 - mean, e1 = x1 - mean;
  float v = e0 * e0 + e1 * e1;
#pragma unroll
  for (int off = 32; off; off >>= 1) v += __shfl_xor(v, off);
  float inv = 1.f / sqrtf(v * (1.f / 128.f) + 1e-5f);
  float* orow = out + (size_t)wid * DD;
  orow[lane] = e0 * inv * g[lane] + b[lane];
  orow[lane + 64] = e1 * inv * g[lane + 64] + b[lane + 64];
}

// conv3 epilogue: emb (pre-ReLU) -> out_stage; ReLU'd -> f_xcur
__global__ void k_emb_relu(const float* __restrict__ in, float* __restrict__ emb_out,
                           float* __restrict__ out, int total) {
  int i = blockIdx.x * 256 + threadIdx.x;
  if (i >= total) return;
  float v = in[i];
  emb_out[i] = v;
  out[i] = fmaxf(v, 0.f);
}

__global__ __launch_bounds__(256) void k_mp2_ls(
    const float* __restrict__ t1, const float* __restrict__ W,
    const float* __restrict__ b2, float* __restrict__ outp, int nrows) {
  int wid = (blockIdx.x * 256 + threadIdx.x) >> 6;
  int lane = threadIdx.x & 63;
  if (wid >= nrows) return;
  const float* row = t1 + (size_t)wid * DD;
  float x0 = row[lane], x1 = row[lane + 64];
  float p0 = x0 * W[lane] + x1 * W[lane + 64];
  float p1 = x0 * W[DD + lane] + x1 * W[DD + 64 + lane];
#pragma unroll
  for (int off = 32; off; off >>= 1) {
    p0 += __shfl_xor(p0, off);
    p1 += __shfl_xor(p1, off);
  }
  if (lane == 0) {
    float v0 = p0 + b2[0], v1 = p1 + b2[1];
    float m = fmaxf(v0, v1);
    float ls = m + logf(__expf(v0 - m) + __expf(v1 - m));
    outp[(size_t)wid * 2 + 0] = v0 - ls;
    outp[(size_t)wid * 2 + 1] = v1 - ls;
  }
}

// final writer: store stage -> d_out in detected dtype
__global__ void k_out(const float* __restrict__ stage, void* __restrict__ dout,
                      int n, const int* flag) {
  const int isf = flag[0];
  int i = blockIdx.x * 256 + threadIdx.x;
  if (i >= n) return;
  if (isf) ((float*)dout)[i] = stage[i];
  else ((u16*)dout)[i] = f2bf(stage[i]);
}

// ---------------------------------------------------------------- launch
extern "C" void kernel_launch(void* const* d_in, const int* in_sizes, int n_in,
                              void* d_out, int out_size, void* d_ws, size_t ws_size,
                              hipStream_t stream) {
  const int* idx_lp = (const int*)d_in[0];
  const int* len_lp = (const int*)d_in[1];
  const int* idx_ns = (const int*)d_in[2];
  const int* len_ns = (const int*)d_in[3];
  const void* x_ref = d_in[4];
  const void* x_def = d_in[5];
  const void* x_pdt = d_in[6];
  const int* eidx   = (const int*)d_in[7];
  const void* ew    = d_in[8];
  const void* lp_emb = d_in[9];
  const void* ns_emb = d_in[10];

  // ---- f32 workspace layout (~74 MB) ----
  int*   flag   = (int*)d_ws;                       // [16]
  float* base   = (float*)d_ws;
  float* WT     = base + 16;                        // 4 x 49,152
  float* lpWihT = WT, *lpWhhT = WT + 49152, *nsWihT = WT + 98304, *nsWhhT = WT + 147456;
  float* smallW = base + 16 + 196608;               // ~200K (see jobs below)
  float* f_hlp  = base + 396640;                    // 7,680,000 (xcur/xw overlay later)
  float* f_xcur = f_hlp;
  float* f_xw   = f_hlp + (size_t)NN * DD;
  float* f_lp   = f_hlp + (size_t)PP * NN * DD;     // 2,560,000
  float* f_ns   = f_lp + (size_t)NN * DD;           // 2,560,000
  float* f_agg  = f_ns + (size_t)NN * DD;           // 2,560,000
  float* f_deg  = f_agg + (size_t)NN * DD;          // 20,000
  float* f_dinv = f_deg + NN;                       // 20,000
  float* stage  = f_dinv + NN;                      // 2,600,000

  // small-tensor convert jobs (f32 offsets within smallW)
  static const int jn[22] = {384, 384, 384, 384, 128, 128, 128, 128, 128, 128,
                             128, 128, 128, 128, 2, 49152, 81920, 16384, 16384,
                             16384, 16384, 256};
  static const int jsrc[22] = {13, 14, 17, 18, 20, 22, 24, 26, 28, 29,
                               30, 31, 32, 34, 36, 19, 21, 23, 25, 27, 33, 35};
  CvtJobs jobs;
  int joff[22];
  {
    int off = 0;
    for (int j = 0; j < 22; ++j) {
      jobs.src[j] = d_in[jsrc[j]];
      jobs.off[j] = off;
      jobs.n[j] = jn[j];
      joff[j] = off;
      off += jn[j];
    }
  }
  float* b_lpbih = smallW + joff[0];
  float* b_lpbhh = smallW + joff[1];
  float* b_nsbih = smallW + joff[2];
  float* b_nsbhh = smallW + joff[3];
  float* b_lpfc  = smallW + joff[4];
  float* b_allfc = smallW + joff[5];
  float* b_conv[3] = {smallW + joff[6], smallW + joff[7], smallW + joff[8]};
  float* g_ln[2] = {smallW + joff[9], smallW + joff[11]};
  float* b_ln[2] = {smallW + joff[10], smallW + joff[12]};
  float* b_mp1   = smallW + joff[13];
  float* b_mp2   = smallW + joff[14];
  float* w_lpfc  = smallW + joff[15];
  float* w_allfc = smallW + joff[16];
  float* w_conv[3] = {smallW + joff[17], smallW + joff[18], smallW + joff[19]};
  float* w_mp1   = smallW + joff[20];
  float* w_mp2   = smallW + joff[21];

  const int* e_src = eidx;
  const int* e_dst = eidx + EE;

  // 0. dtype detection (probe lp_emb)
  k_detect<<<1, 256, 0, stream>>>(lp_emb, flag);

  // 1. small converts + GRU weight transposes
  k_cvt_batch<<<22, 256, 0, stream>>>(jobs, smallW, flag);
  int tg = (384 * DD + 255) / 256;
  k_cvt_transpose<<<tg, 256, 0, stream>>>(d_in[11], lpWihT, 384, DD, flag);
  k_cvt_transpose<<<tg, 256, 0, stream>>>(d_in[12], lpWhhT, 384, DD, flag);
  k_cvt_transpose<<<tg, 256, 0, stream>>>(d_in[15], nsWihT, 384, DD, flag);
  k_cvt_transpose<<<tg, 256, 0, stream>>>(d_in[16], nsWhhT, 384, DD, flag);

  // 2. GRUs (LP slot sg=p*N+i reads row i*P+p -> flat [P,N,D] output layout)
  k_gru<<<PP * NN / 32, 256, 0, stream>>>(lp_emb, idx_lp, len_lp, lpWihT, lpWhhT,
                                          b_lpbih, b_lpbhh, f_hlp, PP * NN, TLP, 0,
                                          NN, flag);
  k_gru<<<NN / 32, 256, 0, stream>>>(ns_emb, idx_ns, len_ns, nsWihT, nsWhhT,
                                     b_nsbih, b_nsbhh, f_ns, NN, TNS, 1, NN, flag);

  // 3. lp_fc: f_hlp flat [3N,128] viewed [N,384] == faithful reshape
  k_gemm<<<NN / 32, 256, 0, stream>>>(f_hlp, nullptr, nullptr, nullptr, nullptr,
                                      nullptr, 0, 384, w_lpfc, b_lpfc, f_lp, flag);
  // 4. all_fc: scramble-gather {pdt, ref, def, lp, ns} -> f_xcur (hlp now dead)
  k_gemm<<<NN / 32, 256, 0, stream>>>(nullptr, x_pdt, x_ref, x_def, f_lp, f_ns,
                                      1, 640, w_allfc, b_allfc, f_xcur, flag);

  // 5. degrees (shared across convs)
  k_deg_init<<<(NN + 255) / 256, 256, 0, stream>>>(f_deg, NN);
  k_deg_acc<<<(EE + 255) / 256, 256, 0, stream>>>(e_dst, ew, f_deg, EE, flag);
  k_dinv<<<(NN + 255) / 256, 256, 0, stream>>>(f_deg, f_dinv, NN);

  // 6. three GCN layers
  int cg = (NN * DD + 255) / 256;
  for (int l = 0; l < 3; ++l) {
    k_gemm<<<NN / 32, 256, 0, stream>>>(f_xcur, nullptr, nullptr, nullptr, nullptr,
                                        nullptr, 0, DD, w_conv[l], nullptr, f_xw, flag);
    k_gcn_self<<<cg, 256, 0, stream>>>(f_xw, f_dinv, b_conv[l], f_agg, NN * DD);
    k_gcn_edges<<<EE / 2, 256, 0, stream>>>(e_src, e_dst, ew, f_dinv, f_xw, f_agg,
                                            EE, flag);
    if (l < 2) {
      k_relu_ln<<<(NN + 3) / 4, 256, 0, stream>>>(f_agg, g_ln[l], b_ln[l], f_xcur, NN);
    } else {
      k_emb_relu<<<cg, 256, 0, stream>>>(f_agg, stage, f_xcur, NN * DD);
    }
  }

  // 7. mp head (no activation between mp1/mp2), log_softmax
  k_gemm<<<NN / 32, 256, 0, stream>>>(f_xcur, nullptr, nullptr, nullptr, nullptr,
                                      nullptr, 0, DD, w_mp1, b_mp1, f_xw, flag);
  k_mp2_ls<<<(NN + 3) / 4, 256, 0, stream>>>(f_xw, w_mp2, b_mp2,
                                             stage + (size_t)NN * DD, NN);

  // 8. store in detected output dtype
  k_out<<<(out_size + 255) / 256, 256, 0, stream>>>(stage, d_out, out_size, flag);
}

// Round 4
// 2553.659 us; speedup vs baseline: 3.2697x; 3.2697x over previous
//
#include <hip/hip_runtime.h>
#include <math.h>

typedef unsigned short u16;
typedef short bf16x8 __attribute__((ext_vector_type(8)));
typedef float f32x16 __attribute__((ext_vector_type(16)));

#define NN 20000
#define PP 3
#define TLP 10
#define TNS 20
#define DD 128
#define EE 640000

__device__ __forceinline__ float bf2f(u16 u) {
  union { unsigned u; float f; } v; v.u = ((unsigned)u) << 16; return v.f;
}
__device__ __forceinline__ u16 f2bf(float f) {
  union { float f; unsigned u; } v; v.f = f;
  unsigned r = v.u + 0x7fffu + ((v.u >> 16) & 1u);
  return (u16)(r >> 16);
}
__device__ __forceinline__ float sigmf(float x) { return 1.f / (1.f + __expf(-x)); }
__device__ __forceinline__ float loadf(const void* p, size_t i, int isf) {
  return isf ? ((const float*)p)[i] : bf2f(((const u16*)p)[i]);
}

// ------------------------------------------------------------- dtype detect
__global__ void k_detect(const void* probe, int* flag) {
  __shared__ int any;
  if (threadIdx.x == 0) any = 0;
  __syncthreads();
  const u16* p = (const u16*)probe;
  int bad = 0;
  for (int i = threadIdx.x; i < 4096; i += 256) {
    int e = (p[2 * i] >> 7) & 0xFF;
    if (e >= 0x9F) bad = 1;
  }
  if (bad) atomicOr(&any, 1);
  __syncthreads();
  if (threadIdx.x == 0) flag[0] = any;  // 1 = f32, 0 = bf16
}

// ------------------------------------------------------------- converters
struct CvtJobs {
  const void* src[24];
  int off[24];
  int n[24];
};

__global__ void k_cvt_batch(CvtJobs jobs, float* dst, const int* flag) {
  const int isf = flag[0];
  const void* s = jobs.src[blockIdx.x];
  float* d = dst + jobs.off[blockIdx.x];
  const int n = jobs.n[blockIdx.x];
  for (int i = threadIdx.x; i < n; i += 256) d[i] = loadf(s, i, isf);
}

// raw (f32 or bf16) -> bf16 table
__global__ void k_cvt_bf16(const void* __restrict__ in, u16* __restrict__ out,
                           int n, const int* flag) {
  const int isf = flag[0];
  int i = blockIdx.x * 256 + threadIdx.x;
  if (i < n) out[i] = f2bf(loadf(in, i, isf));
}

// ---------------------------------------------------------------- GRU (MFMA)
// 32 sequences per block, 256 threads (4 waves). Weights register-resident as
// bf16 B-fragments; H recurrence kept f32 in registers (phase-2 ownership),
// bf16 copy in LDS (A-frag order) for the matmul. 3 barriers/step.
// Wave w owns output cols [32w,32w+32) of each gate (r: n<128, z, n-gate).
__global__ __launch_bounds__(256, 1) void k_gru_mfma(
    const u16* __restrict__ embbf,   // [V,128] bf16
    const int* __restrict__ idx,     // [rows,T]
    const int* __restrict__ lens,    // [rows]
    const u16* __restrict__ Wihbf,   // [384][128] bf16 row-major
    const u16* __restrict__ Whhbf,   // [384][128]
    const float* __restrict__ bih,   // [384] f32
    const float* __restrict__ bhh,   // [384]
    float* __restrict__ Hout,        // [numSeq,128] f32
    int numSeq, int T, int mode, int Nn) {
  __shared__ float P[4][128][33];    // preacts: [r,z,xn,hn][gate-col][m]
  __shared__ u16 Hbf[32 * 128];      // frag-ordered: ((k>>3)*32+m)*8+(k&7)
  __shared__ float bsr[128], bsz[128], binv[128], bhnv[128];
  __shared__ int ivs[32], lenv[32], rowb[32];

  const int tid = threadIdx.x;
  const int w = tid >> 6;
  const int lane = tid & 63;
  const int l31 = lane & 31, lh = lane >> 5;

  if (tid < 32) {
    int sg = blockIdx.x * 32 + tid;
    int row = (mode == 0) ? ((sg % Nn) * PP + sg / Nn) : sg;
    rowb[tid] = row * T;
    lenv[tid] = lens[row];
  }
  for (int d = tid; d < 128; d += 256) {
    bsr[d] = bih[d] + bhh[d];
    bsz[d] = bih[128 + d] + bhh[128 + d];
    binv[d] = bih[256 + d];
    bhnv[d] = bhh[256 + d];
  }
  for (int z = tid; z < 512; z += 256) ((bf16x8*)Hbf)[z] = (bf16x8)(short)0;

  // register-resident weight B-fragments: lane l holds W[n][k] for
  // n = gate*128 + 32w + l31, k = 16kb + 8*lh + j  (16B contiguous)
  bf16x8 wir[8], wiz[8], win[8], whr[8], whz[8], whn[8];
  {
    const size_t rbase = (size_t)(32 * w + l31) * 128 + lh * 8;
#pragma unroll
    for (int kb = 0; kb < 8; ++kb) {
      wir[kb] = *(const bf16x8*)(Wihbf + rbase + kb * 16);
      wiz[kb] = *(const bf16x8*)(Wihbf + (size_t)128 * 128 + rbase + kb * 16);
      win[kb] = *(const bf16x8*)(Wihbf + (size_t)256 * 128 + rbase + kb * 16);
      whr[kb] = *(const bf16x8*)(Whhbf + rbase + kb * 16);
      whz[kb] = *(const bf16x8*)(Whhbf + (size_t)128 * 128 + rbase + kb * 16);
      whn[kb] = *(const bf16x8*)(Whhbf + (size_t)256 * 128 + rbase + kb * 16);
    }
  }

  // f32 recurrence state: thread (m=tid>>3, d0=(tid&7)*16) owns h[d0..d0+15]
  float h[16];
#pragma unroll
  for (int j = 0; j < 16; ++j) h[j] = 0.f;
  const int pm = tid >> 3;
  const int pd0 = (tid & 7) * 16;

  for (int t = 0; t < T; ++t) {
    if (tid < 32) ivs[tid] = idx[rowb[tid] + t];
    __syncthreads();

    // ---- phase 1: MFMA ----
    {
      bf16x8 Xf[8], Hf[8];
      const u16* erow = embbf + (size_t)ivs[l31] * 128 + lh * 8;
#pragma unroll
      for (int kb = 0; kb < 8; ++kb) Xf[kb] = *(const bf16x8*)(erow + kb * 16);
#pragma unroll
      for (int kb = 0; kb < 8; ++kb)
        Hf[kb] = *(const bf16x8*)(Hbf + (2 * kb + lh) * 256 + l31 * 8);

      f32x16 aR = (f32x16)(0.0f), aZ = (f32x16)(0.0f);
      f32x16 aXn = (f32x16)(0.0f), aHn = (f32x16)(0.0f);
#pragma unroll
      for (int kb = 0; kb < 8; ++kb) {
        aR = __builtin_amdgcn_mfma_f32_32x32x16_bf16(Xf[kb], wir[kb], aR, 0, 0, 0);
        aR = __builtin_amdgcn_mfma_f32_32x32x16_bf16(Hf[kb], whr[kb], aR, 0, 0, 0);
        aZ = __builtin_amdgcn_mfma_f32_32x32x16_bf16(Xf[kb], wiz[kb], aZ, 0, 0, 0);
        aZ = __builtin_amdgcn_mfma_f32_32x32x16_bf16(Hf[kb], whz[kb], aZ, 0, 0, 0);
        aXn = __builtin_amdgcn_mfma_f32_32x32x16_bf16(Xf[kb], win[kb], aXn, 0, 0, 0);
        aHn = __builtin_amdgcn_mfma_f32_32x32x16_bf16(Hf[kb], whn[kb], aHn, 0, 0, 0);
      }
      // store preacts: C/D layout col=lane&31, row=(reg&3)+8*(reg>>2)+4*lh
      const int cl = 32 * w + l31;
#pragma unroll
      for (int rg = 0; rg < 4; ++rg) {
        const int m = 8 * rg + 4 * lh;
#pragma unroll
        for (int q = 0; q < 4; ++q) {
          P[0][cl][m + q] = aR[rg * 4 + q];
          P[1][cl][m + q] = aZ[rg * 4 + q];
          P[2][cl][m + q] = aXn[rg * 4 + q];
          P[3][cl][m + q] = aHn[rg * 4 + q];
        }
      }
    }
    __syncthreads();

    // ---- phase 2: gates + h update (f32 in registers) ----
    {
      const bool upd = (t < lenv[pm]);
#pragma unroll
      for (int j = 0; j < 16; ++j) {
        const int d = pd0 + j;
        float r = sigmf(P[0][d][pm] + bsr[d]);
        float z = sigmf(P[1][d][pm] + bsz[d]);
        float nn_ = tanhf(P[2][d][pm] + binv[d] + r * (P[3][d][pm] + bhnv[d]));
        float hnew = (1.f - z) * nn_ + z * h[j];
        if (upd) h[j] = hnew;
      }
      bf16x8 v0, v1;
#pragma unroll
      for (int j = 0; j < 8; ++j) {
        v0[j] = (short)f2bf(h[j]);
        v1[j] = (short)f2bf(h[8 + j]);
      }
      const int o0 = pd0 >> 3;
      *(bf16x8*)(Hbf + (o0 * 32 + pm) * 8) = v0;
      *(bf16x8*)(Hbf + ((o0 + 1) * 32 + pm) * 8) = v1;
    }
    __syncthreads();
  }

  // write final h (f32)
  {
    int sg = blockIdx.x * 32 + pm;
    if (sg < numSeq) {
      float* dst = Hout + (size_t)sg * DD + pd0;
#pragma unroll
      for (int j = 0; j < 16; j += 4)
        *(float4*)(dst + j) = make_float4(h[j], h[j + 1], h[j + 2], h[j + 3]);
    }
  }
}

// ---------------------------------------------------------------- GEMM (f32 VALU)
// C[M x 128] f32 = A[M x K] @ W[128 x K].T + bias.
// mode 0: A flat f32. mode 1: faithful scramble over stack [5N,128].
__global__ __launch_bounds__(256) void k_gemm(
    const float* __restrict__ A, const void* __restrict__ R0,
    const void* __restrict__ R1, const void* __restrict__ R2,
    const float* __restrict__ A3, const float* __restrict__ A4,
    int mode, int K, const float* __restrict__ W,
    const float* __restrict__ bias, float* __restrict__ C, const int* flag) {
  __shared__ float As[32][33];
  __shared__ float Bt[32][DD + 4];
  const int isf = flag[0];
  const int tid = threadIdx.x;
  const int ty = tid >> 4, tx = tid & 15;
  const int s0 = ty * 2, d0 = tx * 8;
  const int rbase = blockIdx.x * 32;
  const int sl = tid >> 3, ko4 = (tid & 7) << 2;
  const int dW = tid >> 1, koW = (tid & 1) << 4;

  float acc[2][8];
#pragma unroll
  for (int m = 0; m < 2; ++m)
#pragma unroll
    for (int n = 0; n < 8; ++n) acc[m][n] = 0.f;

  for (int k0 = 0; k0 < K; k0 += 32) {
    {
      float v0, v1, v2, v3;
      if (mode == 0) {
        float4 v = *(const float4*)(A + (size_t)(rbase + sl) * K + k0 + ko4);
        v0 = v.x; v1 = v.y; v2 = v.z; v3 = v.w;
      } else {
        int r5 = 5 * (rbase + sl) + (k0 >> 7);
        int slot = r5 / NN;
        int inner = r5 - slot * NN;
        size_t base = (size_t)inner * DD + (k0 & 127) + ko4;
        if (slot < 3) {
          const void* p = (slot == 0) ? R0 : (slot == 1) ? R1 : R2;
          v0 = loadf(p, base + 0, isf); v1 = loadf(p, base + 1, isf);
          v2 = loadf(p, base + 2, isf); v3 = loadf(p, base + 3, isf);
        } else {
          const float* p = (slot == 3) ? A3 : A4;
          float4 v = *(const float4*)(p + base);
          v0 = v.x; v1 = v.y; v2 = v.z; v3 = v.w;
        }
      }
      As[ko4 + 0][sl] = v0; As[ko4 + 1][sl] = v1;
      As[ko4 + 2][sl] = v2; As[ko4 + 3][sl] = v3;
    }
    {
      const float* srcw = W + (size_t)dW * K + k0 + koW;
#pragma unroll
      for (int q = 0; q < 4; ++q) {
        float4 v = *(const float4*)(srcw + q * 4);
        Bt[koW + q * 4 + 0][dW] = v.x;
        Bt[koW + q * 4 + 1][dW] = v.y;
        Bt[koW + q * 4 + 2][dW] = v.z;
        Bt[koW + q * 4 + 3][dW] = v.w;
      }
    }
    __syncthreads();
#pragma unroll
    for (int kk = 0; kk < 32; ++kk) {
      float a0 = As[kk][s0];
      float a1 = As[kk][s0 + 1];
      float4 b0 = *(const float4*)&Bt[kk][d0];
      float4 b1 = *(const float4*)&Bt[kk][d0 + 4];
      float bv[8] = {b0.x, b0.y, b0.z, b0.w, b1.x, b1.y, b1.z, b1.w};
#pragma unroll
      for (int n = 0; n < 8; ++n) {
        acc[0][n] += a0 * bv[n];
        acc[1][n] += a1 * bv[n];
      }
    }
    __syncthreads();
  }
#pragma unroll
  for (int m = 0; m < 2; ++m) {
    int r = rbase + s0 + m;
    float b0 = bias ? bias[d0 + 0] : 0.f, b1 = bias ? bias[d0 + 1] : 0.f;
    float b2 = bias ? bias[d0 + 2] : 0.f, b3 = bias ? bias[d0 + 3] : 0.f;
    float b4 = bias ? bias[d0 + 4] : 0.f, b5 = bias ? bias[d0 + 5] : 0.f;
    float b6 = bias ? bias[d0 + 6] : 0.f, b7 = bias ? bias[d0 + 7] : 0.f;
    float4* dst = (float4*)(C + (size_t)r * DD + d0);
    dst[0] = make_float4(acc[m][0] + b0, acc[m][1] + b1, acc[m][2] + b2, acc[m][3] + b3);
    dst[1] = make_float4(acc[m][4] + b4, acc[m][5] + b5, acc[m][6] + b6, acc[m][7] + b7);
  }
}

// ---------------------------------------------------------------- small kernels
__global__ void k_deg_init(float* __restrict__ deg, int n) {
  int i = blockIdx.x * 256 + threadIdx.x;
  if (i < n) deg[i] = 1.f;
}

__global__ void k_deg_acc(const int* __restrict__ dst, const void* __restrict__ w,
                          float* __restrict__ deg, int E, const int* flag) {
  const int isf = flag[0];
  int e = blockIdx.x * 256 + threadIdx.x;
  if (e < E) atomicAdd(&deg[dst[e]], loadf(w, e, isf));
}

__global__ void k_dinv(const float* __restrict__ deg, float* __restrict__ dinv, int n) {
  int i = blockIdx.x * 256 + threadIdx.x;
  if (i < n) dinv[i] = 1.f / sqrtf(deg[i]);
}

__global__ void k_gcn_self(const float* __restrict__ xw, const float* __restrict__ dinv,
                           const float* __restrict__ bias, float* __restrict__ out,
                           int total) {
  int i = blockIdx.x * 256 + threadIdx.x;
  if (i >= total) return;
  int r = i >> 7, d = i & 127;
  float di = dinv[r];
  out[i] = bias[d] + di * di * xw[i];
}

__global__ __launch_bounds__(256) void k_gcn_edges(
    const int* __restrict__ src, const int* __restrict__ dst,
    const void* __restrict__ w, const float* __restrict__ dinv,
    const float* __restrict__ xw, float* __restrict__ out, int E, const int* flag) {
  const int isf = flag[0];
  int e = blockIdx.x * 2 + (threadIdx.x >> 7);
  int d = threadIdx.x & 127;
  if (e >= E) return;
  int s = src[e], t = dst[e];
  float coef = dinv[s] * loadf(w, e, isf) * dinv[t];
  atomicAdd(&out[(size_t)t * DD + d], coef * xw[(size_t)s * DD + d]);
}

__global__ __launch_bounds__(256) void k_relu_ln(
    const float* __restrict__ in, const float* __restrict__ g,
    const float* __restrict__ b, float* __restrict__ out, int nrows) {
  int wid = (blockIdx.x * 256 + threadIdx.x) >> 6;
  int lane = threadIdx.x & 63;
  if (wid >= nrows) return;
  const float* row = in + (size_t)wid * DD;
  float x0 = fmaxf(row[lane], 0.f), x1 = fmaxf(row[lane + 64], 0.f);
  float s = x0 + x1;
#pragma unroll
  for (int off = 32; off; off >>= 1) s += __shfl_xor(s, off);
  float mean = s * (1.f / 128.f);
  float e0 = x0 - mean, e1 = x1 - mean;
  float v = e0 * e0 + e1 * e1;
#pragma unroll
  for (int off = 32; off; off >>= 1) v += __shfl_xor(v, off);
  float inv = 1.f / sqrtf(v * (1.f / 128.f) + 1e-5f);
  float* orow = out + (size_t)wid * DD;
  orow[lane] = e0 * inv * g[lane] + b[lane];
  orow[lane + 64] = e1 * inv * g[lane + 64] + b[lane + 64];
}

__global__ void k_emb_relu(const float* __restrict__ in, float* __restrict__ emb_out,
                           float* __restrict__ out, int total) {
  int i = blockIdx.x * 256 + threadIdx.x;
  if (i >= total) return;
  float v = in[i];
  emb_out[i] = v;
  out[i] = fmaxf(v, 0.f);
}

__global__ __launch_bounds__(256) void k_mp2_ls(
    const float* __restrict__ t1, const float* __restrict__ W,
    const float* __restrict__ b2, float* __restrict__ outp, int nrows) {
  int wid = (blockIdx.x * 256 + threadIdx.x) >> 6;
  int lane = threadIdx.x & 63;
  if (wid >= nrows) return;
  const float* row = t1 + (size_t)wid * DD;
  float x0 = row[lane], x1 = row[lane + 64];
  float p0 = x0 * W[lane] + x1 * W[lane + 64];
  float p1 = x0 * W[DD + lane] + x1 * W[DD + 64 + lane];
#pragma unroll
  for (int off = 32; off; off >>= 1) {
    p0 += __shfl_xor(p0, off);
    p1 += __shfl_xor(p1, off);
  }
  if (lane == 0) {
    float v0 = p0 + b2[0], v1 = p1 + b2[1];
    float m = fmaxf(v0, v1);
    float ls = m + logf(__expf(v0 - m) + __expf(v1 - m));
    outp[(size_t)wid * 2 + 0] = v0 - ls;
    outp[(size_t)wid * 2 + 1] = v1 - ls;
  }
}

__global__ void k_out(const float* __restrict__ stage, void* __restrict__ dout,
                      int n, const int* flag) {
  const int isf = flag[0];
  int i = blockIdx.x * 256 + threadIdx.x;
  if (i >= n) return;
  if (isf) ((float*)dout)[i] = stage[i];
  else ((u16*)dout)[i] = f2bf(stage[i]);
}

// ---------------------------------------------------------------- launch
extern "C" void kernel_launch(void* const* d_in, const int* in_sizes, int n_in,
                              void* d_out, int out_size, void* d_ws, size_t ws_size,
                              hipStream_t stream) {
  const int* idx_lp = (const int*)d_in[0];
  const int* len_lp = (const int*)d_in[1];
  const int* idx_ns = (const int*)d_in[2];
  const int* len_ns = (const int*)d_in[3];
  const void* x_ref = d_in[4];
  const void* x_def = d_in[5];
  const void* x_pdt = d_in[6];
  const int* eidx   = (const int*)d_in[7];
  const void* ew    = d_in[8];
  const void* lp_emb = d_in[9];
  const void* ns_emb = d_in[10];

  // ---- workspace layout (~77 MB) ----
  int*   flag   = (int*)d_ws;
  float* base   = (float*)d_ws;
  float* smallW = base + 16;                        // 199,682 f32
  float* f_hlp  = base + 199700;                    // [3N,128] (xcur/xw overlay)
  float* f_xcur = f_hlp;
  float* f_xw   = f_hlp + (size_t)NN * DD;
  float* f_lp   = f_hlp + (size_t)PP * NN * DD;
  float* f_ns   = f_lp + (size_t)NN * DD;
  float* f_agg  = f_ns + (size_t)NN * DD;
  float* f_deg  = f_agg + (size_t)NN * DD;
  float* f_dinv = f_deg + NN;
  float* stage  = f_dinv + NN;
  u16* ub       = (u16*)(stage + (size_t)NN * DD + 2 * NN);  // bf16 region
  u16* embbf_lp = ub;                                // 640,000
  u16* embbf_ns = embbf_lp + 640000;                 // 1,280,000
  u16* wb_lpih  = embbf_ns + 1280000;                // 49,152 each
  u16* wb_lphh  = wb_lpih + 49152;
  u16* wb_nsih  = wb_lphh + 49152;
  u16* wb_nshh  = wb_nsih + 49152;

  // small-tensor f32 conversions
  static const int jn[22] = {384, 384, 384, 384, 128, 128, 128, 128, 128, 128,
                             128, 128, 128, 128, 2, 49152, 81920, 16384, 16384,
                             16384, 16384, 256};
  static const int jsrc[22] = {13, 14, 17, 18, 20, 22, 24, 26, 28, 29,
                               30, 31, 32, 34, 36, 19, 21, 23, 25, 27, 33, 35};
  CvtJobs jobs;
  int joff[22];
  {
    int off = 0;
    for (int j = 0; j < 22; ++j) {
      jobs.src[j] = d_in[jsrc[j]];
      jobs.off[j] = off;
      jobs.n[j] = jn[j];
      joff[j] = off;
      off += jn[j];
    }
  }
  float* b_lpbih = smallW + joff[0];
  float* b_lpbhh = smallW + joff[1];
  float* b_nsbih = smallW + joff[2];
  float* b_nsbhh = smallW + joff[3];
  float* b_lpfc  = smallW + joff[4];
  float* b_allfc = smallW + joff[5];
  float* b_conv[3] = {smallW + joff[6], smallW + joff[7], smallW + joff[8]};
  float* g_ln[2] = {smallW + joff[9], smallW + joff[11]};
  float* b_ln[2] = {smallW + joff[10], smallW + joff[12]};
  float* b_mp1   = smallW + joff[13];
  float* b_mp2   = smallW + joff[14];
  float* w_lpfc  = smallW + joff[15];
  float* w_allfc = smallW + joff[16];
  float* w_conv[3] = {smallW + joff[17], smallW + joff[18], smallW + joff[19]};
  float* w_mp1   = smallW + joff[20];
  float* w_mp2   = smallW + joff[21];

  const int* e_src = eidx;
  const int* e_dst = eidx + EE;

  // 0. dtype detection
  k_detect<<<1, 256, 0, stream>>>(lp_emb, flag);

  // 1. conversions: small f32 tensors + bf16 tables for MFMA GRU
  k_cvt_batch<<<22, 256, 0, stream>>>(jobs, smallW, flag);
  k_cvt_bf16<<<(640000 + 255) / 256, 256, 0, stream>>>(lp_emb, embbf_lp, 640000, flag);
  k_cvt_bf16<<<(1280000 + 255) / 256, 256, 0, stream>>>(ns_emb, embbf_ns, 1280000, flag);
  k_cvt_bf16<<<192, 256, 0, stream>>>(d_in[11], wb_lpih, 49152, flag);
  k_cvt_bf16<<<192, 256, 0, stream>>>(d_in[12], wb_lphh, 49152, flag);
  k_cvt_bf16<<<192, 256, 0, stream>>>(d_in[15], wb_nsih, 49152, flag);
  k_cvt_bf16<<<192, 256, 0, stream>>>(d_in[16], wb_nshh, 49152, flag);

  // 2. GRUs via MFMA (LP slot sg=p*N+i reads row i*P+p -> [P,N,D] flat layout)
  k_gru_mfma<<<PP * NN / 32, 256, 0, stream>>>(embbf_lp, idx_lp, len_lp, wb_lpih,
                                               wb_lphh, b_lpbih, b_lpbhh, f_hlp,
                                               PP * NN, TLP, 0, NN);
  k_gru_mfma<<<NN / 32, 256, 0, stream>>>(embbf_ns, idx_ns, len_ns, wb_nsih,
                                          wb_nshh, b_nsbih, b_nsbhh, f_ns,
                                          NN, TNS, 1, NN);

  // 3. lp_fc: f_hlp flat [3N,128] viewed [N,384] == faithful reshape
  k_gemm<<<NN / 32, 256, 0, stream>>>(f_hlp, nullptr, nullptr, nullptr, nullptr,
                                      nullptr, 0, 384, w_lpfc, b_lpfc, f_lp, flag);
  // 4. all_fc: scramble-gather {pdt, ref, def, lp, ns} -> f_xcur
  k_gemm<<<NN / 32, 256, 0, stream>>>(nullptr, x_pdt, x_ref, x_def, f_lp, f_ns,
                                      1, 640, w_allfc, b_allfc, f_xcur, flag);

  // 5. degrees
  k_deg_init<<<(NN + 255) / 256, 256, 0, stream>>>(f_deg, NN);
  k_deg_acc<<<(EE + 255) / 256, 256, 0, stream>>>(e_dst, ew, f_deg, EE, flag);
  k_dinv<<<(NN + 255) / 256, 256, 0, stream>>>(f_deg, f_dinv, NN);

  // 6. three GCN layers
  int cg = (NN * DD + 255) / 256;
  for (int l = 0; l < 3; ++l) {
    k_gemm<<<NN / 32, 256, 0, stream>>>(f_xcur, nullptr, nullptr, nullptr, nullptr,
                                        nullptr, 0, DD, w_conv[l], nullptr, f_xw, flag);
    k_gcn_self<<<cg, 256, 0, stream>>>(f_xw, f_dinv, b_conv[l], f_agg, NN * DD);
    k_gcn_edges<<<EE / 2, 256, 0, stream>>>(e_src, e_dst, ew, f_dinv, f_xw, f_agg,
                                            EE, flag);
    if (l < 2) {
      k_relu_ln<<<(NN + 3) / 4, 256, 0, stream>>>(f_agg, g_ln[l], b_ln[l], f_xcur, NN);
    } else {
      k_emb_relu<<<cg, 256, 0, stream>>>(f_agg, stage, f_xcur, NN * DD);
    }
  }

  // 7. mp head + log_softmax
  k_gemm<<<NN / 32, 256, 0, stream>>>(f_xcur, nullptr, nullptr, nullptr, nullptr,
                                      nullptr, 0, DD, w_mp1, b_mp1, f_xw, flag);
  k_mp2_ls<<<(NN + 3) / 4, 256, 0, stream>>>(f_xw, w_mp2, b_mp2,
                                             stage + (size_t)NN * DD, NN);

  // 8. store in detected output dtype
  k_out<<<(out_size + 255) / 256, 256, 0, stream>>>(stage, d_out, out_size, flag);
}

// Round 5
// 1812.245 us; speedup vs baseline: 4.6073x; 1.4091x over previous
//
#include <hip/hip_runtime.h>
#include <math.h>

typedef unsigned short u16;
typedef short bf16x8 __attribute__((ext_vector_type(8)));
typedef float f32x16 __attribute__((ext_vector_type(16)));

#define NN 20000
#define PP 3
#define TLP 10
#define TNS 20
#define DD 128
#define EE 640000

__device__ __forceinline__ float bf2f(u16 u) {
  union { unsigned u; float f; } v; v.u = ((unsigned)u) << 16; return v.f;
}
__device__ __forceinline__ u16 f2bf(float f) {
  union { float f; unsigned u; } v; v.f = f;
  unsigned r = v.u + 0x7fffu + ((v.u >> 16) & 1u);
  return (u16)(r >> 16);
}
__device__ __forceinline__ float fsig(float x) {
  return __fdividef(1.f, 1.f + __expf(-x));
}
__device__ __forceinline__ float ftanh(float x) {
  float t = __expf(-2.f * fabsf(x));
  float r = __fdividef(1.f - t, 1.f + t);
  return copysignf(r, x);
}
__device__ __forceinline__ float loadf(const void* p, size_t i, int isf) {
  return isf ? ((const float*)p)[i] : bf2f(((const u16*)p)[i]);
}

// ------------------------------------------------------------- dtype detect
__global__ void k_detect(const void* probe, int* flag) {
  __shared__ int any;
  if (threadIdx.x == 0) any = 0;
  __syncthreads();
  const u16* p = (const u16*)probe;
  int bad = 0;
  for (int i = threadIdx.x; i < 4096; i += 256) {
    int e = (p[2 * i] >> 7) & 0xFF;
    if (e >= 0x9F) bad = 1;
  }
  if (bad) atomicOr(&any, 1);
  __syncthreads();
  if (threadIdx.x == 0) flag[0] = any;  // 1 = f32, 0 = bf16
}

// ------------------------------------------------------------- converters
struct CvtJobs {
  const void* src[16];
  int off[16];
  int n[16];
};

__global__ void k_cvt_batch(CvtJobs jobs, float* dst, const int* flag) {
  const int isf = flag[0];
  const void* s = jobs.src[blockIdx.x];
  float* d = dst + jobs.off[blockIdx.x];
  const int n = jobs.n[blockIdx.x];
  for (int i = threadIdx.x; i < n; i += 256) d[i] = loadf(s, i, isf);
}

struct CvtJobsB {
  const void* src[12];
  int off[12];
  int n[12];
};

// raw (f32 or bf16) -> bf16, 64 blocks per job
__global__ void k_cvtb(CvtJobsB j, u16* __restrict__ dst, const int* flag) {
  const int isf = flag[0];
  const int job = blockIdx.x >> 6;
  const int chunk = blockIdx.x & 63;
  const void* s = j.src[job];
  u16* d = dst + j.off[job];
  const int n = j.n[job];
  for (int i = chunk * 256 + threadIdx.x; i < n; i += 64 * 256)
    d[i] = f2bf(loadf(s, i, isf));
}

// ---------------------------------------------------------------- GRU (MFMA, C-layout gates)
// 32 seqs/block, 256 thr (4 waves). Wave w owns gate cols d=[32w,32w+32).
// Accumulators stay in C layout; gates computed in-register (no preact LDS).
// h state: f32 regs in C layout; bf16 copy in LDS (A-frag order) for matmul.
// 2 barriers/step.
__global__ __launch_bounds__(256, 1) void k_gru2(
    const u16* __restrict__ embbf,   // [V,128] bf16
    const int* __restrict__ idx,     // [rows,T]
    const int* __restrict__ lens,    // [rows]
    const u16* __restrict__ Wih,     // [384][128] bf16
    const u16* __restrict__ Whh,     // [384][128] bf16
    const float* __restrict__ bih,   // [384] f32
    const float* __restrict__ bhh,   // [384] f32
    u16* __restrict__ Houtbf,        // [numSeq,128] bf16
    int numSeq, int T, int mode, int Nn) {
  __shared__ u16 Hbf[4096];          // A-frag order: ((k>>3)*32+m)*8+(k&7)
  __shared__ int ivs[32], rowb[32], lenv_s[32];

  const int tid = threadIdx.x;
  const int w = tid >> 6, lane = tid & 63;
  const int l31 = lane & 31, lh = lane >> 5;
  const int d = 32 * w + l31;        // this lane's gate column

  if (tid < 32) {
    int sg = blockIdx.x * 32 + tid;
    int row = (mode == 0) ? ((sg % Nn) * PP + sg / Nn) : sg;
    rowb[tid] = row * T;
    lenv_s[tid] = lens[row];
  }
  for (int z = tid; z < 512; z += 256) ((bf16x8*)Hbf)[z] = (bf16x8)(short)0;

  // register-resident weight B-frags: lane holds W[n=d (+gate*128)][k]
  bf16x8 wir[8], wiz[8], win[8], whr[8], whz[8], whn[8];
  {
    const size_t rb = (size_t)d * 128 + lh * 8;
#pragma unroll
    for (int kb = 0; kb < 8; ++kb) {
      wir[kb] = *(const bf16x8*)(Wih + rb + kb * 16);
      wiz[kb] = *(const bf16x8*)(Wih + 16384 + rb + kb * 16);
      win[kb] = *(const bf16x8*)(Wih + 32768 + rb + kb * 16);
      whr[kb] = *(const bf16x8*)(Whh + rb + kb * 16);
      whz[kb] = *(const bf16x8*)(Whh + 16384 + rb + kb * 16);
      whn[kb] = *(const bf16x8*)(Whh + 32768 + rb + kb * 16);
    }
  }
  const float bsr = bih[d] + bhh[d];
  const float bsz = bih[128 + d] + bhh[128 + d];
  const float bin = bih[256 + d];
  const float bhn = bhh[256 + d];

  __syncthreads();
  int lenr[16];
#pragma unroll
  for (int rg = 0; rg < 16; ++rg)
    lenr[rg] = lenv_s[(rg & 3) + 8 * (rg >> 2) + 4 * lh];

  float h[16];
#pragma unroll
  for (int rg = 0; rg < 16; ++rg) h[rg] = 0.f;

  const int dhi = d >> 3, dlo = d & 7;

  for (int t = 0; t < T; ++t) {
    if (tid < 32) ivs[tid] = idx[rowb[tid] + t];
    __syncthreads();  // ivs + prev-step Hbf writes visible

    bf16x8 Xf[8], Hf[8];
    {
      const u16* erow = embbf + (size_t)ivs[l31] * 128 + lh * 8;
#pragma unroll
      for (int kb = 0; kb < 8; ++kb) Xf[kb] = *(const bf16x8*)(erow + kb * 16);
#pragma unroll
      for (int kb = 0; kb < 8; ++kb)
        Hf[kb] = *(const bf16x8*)(Hbf + (2 * kb + lh) * 256 + l31 * 8);
    }
    __syncthreads();  // all reads done before any wave rewrites Hbf

    f32x16 aR = (f32x16)(0.f), aZ = (f32x16)(0.f);
    f32x16 aXn = (f32x16)(0.f), aHn = (f32x16)(0.f);
#pragma unroll
    for (int kb = 0; kb < 8; ++kb) {
      aR = __builtin_amdgcn_mfma_f32_32x32x16_bf16(Xf[kb], wir[kb], aR, 0, 0, 0);
      aZ = __builtin_amdgcn_mfma_f32_32x32x16_bf16(Xf[kb], wiz[kb], aZ, 0, 0, 0);
      aXn = __builtin_amdgcn_mfma_f32_32x32x16_bf16(Xf[kb], win[kb], aXn, 0, 0, 0);
      aHn = __builtin_amdgcn_mfma_f32_32x32x16_bf16(Hf[kb], whn[kb], aHn, 0, 0, 0);
      aR = __builtin_amdgcn_mfma_f32_32x32x16_bf16(Hf[kb], whr[kb], aR, 0, 0, 0);
      aZ = __builtin_amdgcn_mfma_f32_32x32x16_bf16(Hf[kb], whz[kb], aZ, 0, 0, 0);
    }

    // gates in C layout: reg rg <-> (m=(rg&3)+8*(rg>>2)+4*lh, this lane's d)
#pragma unroll
    for (int rg = 0; rg < 16; ++rg) {
      float r = fsig(aR[rg] + bsr);
      float z = fsig(aZ[rg] + bsz);
      float nn_ = ftanh(aXn[rg] + bin + r * (aHn[rg] + bhn));
      float hnew = (1.f - z) * nn_ + z * h[rg];
      h[rg] = (t < lenr[rg]) ? hnew : h[rg];  // pack_padded mask
    }
    // write bf16 h slice to Hbf in A-frag order
#pragma unroll
    for (int rg = 0; rg < 16; ++rg) {
      int m = (rg & 3) + 8 * (rg >> 2) + 4 * lh;
      Hbf[(dhi * 32 + m) * 8 + dlo] = f2bf(h[rg]);
    }
  }

  const int sgb = blockIdx.x * 32;
#pragma unroll
  for (int rg = 0; rg < 16; ++rg) {
    int m = (rg & 3) + 8 * (rg >> 2) + 4 * lh;
    Houtbf[(size_t)(sgb + m) * 128 + d] = f2bf(h[rg]);
  }
}

// ---------------------------------------------------------------- GEMM (MFMA, LDS-free)
// C[M x 128] = A[M x K](bf16) @ W[128 x K]^T(bf16) + bias; f32 or bf16 out.
// Block: 64 rows x 128 cols; wave w: rows 32*(w&1), col-half 64*(w>>1).
// mode 1: faithful scramble over [5N,128] stack; slots 0-2 raw (f32/bf16).
__global__ __launch_bounds__(256) void k_gemm_mfma(
    const void* __restrict__ A0, const void* __restrict__ A1,
    const void* __restrict__ A2, const u16* __restrict__ A3,
    const u16* __restrict__ A4, int mode, int K,
    const u16* __restrict__ W, const float* __restrict__ bias,
    void* __restrict__ Cout, int out_bf, int M, const int* __restrict__ flag) {
  const int isf = flag[0];
  const int tid = threadIdx.x;
  const int w = tid >> 6, lane = tid & 63;
  const int l31 = lane & 31, lh = lane >> 5;
  const int w01 = w & 1, w23 = w >> 1;
  const int mbase = blockIdx.x * 64 + 32 * w01;
  const int row = mbase + l31;
  const int rowc = row < M ? row : M - 1;

  f32x16 acc0 = (f32x16)(0.f), acc1 = (f32x16)(0.f);
  const int nk = K >> 4;
  for (int kb = 0; kb < nk; ++kb) {
    bf16x8 a;
    if (mode == 0) {
      a = *(const bf16x8*)((const u16*)A0 + (size_t)rowc * K + kb * 16 + lh * 8);
    } else {
      int r5 = 5 * rowc + (kb >> 3);
      int slot = r5 / NN;
      int inner = r5 - slot * NN;
      int koff = (kb & 7) * 16 + lh * 8;
      if (slot < 3) {
        const void* p = (slot == 0) ? A0 : (slot == 1) ? A1 : A2;
        if (isf) {
          const float* fp = (const float*)p + (size_t)inner * 128 + koff;
          float4 v0 = *(const float4*)fp;
          float4 v1 = *(const float4*)(fp + 4);
          a[0] = (short)f2bf(v0.x); a[1] = (short)f2bf(v0.y);
          a[2] = (short)f2bf(v0.z); a[3] = (short)f2bf(v0.w);
          a[4] = (short)f2bf(v1.x); a[5] = (short)f2bf(v1.y);
          a[6] = (short)f2bf(v1.z); a[7] = (short)f2bf(v1.w);
        } else {
          a = *(const bf16x8*)((const u16*)p + (size_t)inner * 128 + koff);
        }
      } else {
        const u16* p = (slot == 3) ? A3 : A4;
        a = *(const bf16x8*)(p + (size_t)inner * 128 + koff);
      }
    }
    const u16* wp = W + (size_t)(64 * w23 + l31) * K + kb * 16 + lh * 8;
    bf16x8 b0 = *(const bf16x8*)wp;
    bf16x8 b1 = *(const bf16x8*)(wp + (size_t)32 * K);
    acc0 = __builtin_amdgcn_mfma_f32_32x32x16_bf16(a, b0, acc0, 0, 0, 0);
    acc1 = __builtin_amdgcn_mfma_f32_32x32x16_bf16(a, b1, acc1, 0, 0, 0);
  }
  const int col0 = 64 * w23 + l31;
  const float bv0 = bias ? bias[col0] : 0.f;
  const float bv1 = bias ? bias[col0 + 32] : 0.f;
#pragma unroll
  for (int rg = 0; rg < 16; ++rg) {
    int m = (rg & 3) + 8 * (rg >> 2) + 4 * lh;
    int grow = mbase + m;
    if (grow < M) {
      float v0 = acc0[rg] + bv0, v1 = acc1[rg] + bv1;
      if (out_bf) {
        ((u16*)Cout)[(size_t)grow * 128 + col0] = f2bf(v0);
        ((u16*)Cout)[(size_t)grow * 128 + col0 + 32] = f2bf(v1);
      } else {
        ((float*)Cout)[(size_t)grow * 128 + col0] = v0;
        ((float*)Cout)[(size_t)grow * 128 + col0 + 32] = v1;
      }
    }
  }
}

// ---------------------------------------------------------------- small kernels
__global__ void k_deg_init(float* __restrict__ deg, int n) {
  int i = blockIdx.x * 256 + threadIdx.x;
  if (i < n) deg[i] = 1.f;
}

__global__ void k_deg_acc(const int* __restrict__ dst, const void* __restrict__ w,
                          float* __restrict__ deg, int E, const int* flag) {
  const int isf = flag[0];
  int e = blockIdx.x * 256 + threadIdx.x;
  if (e < E) atomicAdd(&deg[dst[e]], loadf(w, e, isf));
}

__global__ void k_dinv(const float* __restrict__ deg, float* __restrict__ dinv, int n) {
  int i = blockIdx.x * 256 + threadIdx.x;
  if (i < n) dinv[i] = 1.f / sqrtf(deg[i]);
}

__global__ void k_gcn_self(const float* __restrict__ xw, const float* __restrict__ dinv,
                           const float* __restrict__ bias, float* __restrict__ out,
                           int total) {
  int i = blockIdx.x * 256 + threadIdx.x;
  if (i >= total) return;
  int r = i >> 7, d = i & 127;
  float di = dinv[r];
  out[i] = bias[d] + di * di * xw[i];
}

__global__ __launch_bounds__(256) void k_gcn_edges(
    const int* __restrict__ src, const int* __restrict__ dst,
    const void* __restrict__ w, const float* __restrict__ dinv,
    const float* __restrict__ xw, float* __restrict__ out, int E, const int* flag) {
  const int isf = flag[0];
  int e = blockIdx.x * 2 + (threadIdx.x >> 7);
  int d = threadIdx.x & 127;
  if (e >= E) return;
  int s = src[e], t = dst[e];
  float coef = dinv[s] * loadf(w, e, isf) * dinv[t];
  atomicAdd(&out[(size_t)t * DD + d], coef * xw[(size_t)s * DD + d]);
}

// ReLU + LayerNorm, bf16 out (feeds next conv GEMM)
__global__ __launch_bounds__(256) void k_relu_ln(
    const float* __restrict__ in, const float* __restrict__ g,
    const float* __restrict__ b, u16* __restrict__ out, int nrows) {
  int wid = (blockIdx.x * 256 + threadIdx.x) >> 6;
  int lane = threadIdx.x & 63;
  if (wid >= nrows) return;
  const float* row = in + (size_t)wid * DD;
  float x0 = fmaxf(row[lane], 0.f), x1 = fmaxf(row[lane + 64], 0.f);
  float s = x0 + x1;
#pragma unroll
  for (int off = 32; off; off >>= 1) s += __shfl_xor(s, off);
  float mean = s * (1.f / 128.f);
  float e0 = x0 - mean, e1 = x1 - mean;
  float v = e0 * e0 + e1 * e1;
#pragma unroll
  for (int off = 32; off; off >>= 1) v += __shfl_xor(v, off);
  float inv = 1.f / sqrtf(v * (1.f / 128.f) + 1e-5f);
  u16* orow = out + (size_t)wid * DD;
  orow[lane] = f2bf(e0 * inv * g[lane] + b[lane]);
  orow[lane + 64] = f2bf(e1 * inv * g[lane + 64] + b[lane + 64]);
}

// conv3 epilogue: emb (pre-ReLU, f32) -> stage; ReLU'd bf16 -> mp1 input
__global__ void k_emb_relu(const float* __restrict__ in, float* __restrict__ emb_out,
                           u16* __restrict__ out, int total) {
  int i = blockIdx.x * 256 + threadIdx.x;
  if (i >= total) return;
  float v = in[i];
  emb_out[i] = v;
  out[i] = f2bf(fmaxf(v, 0.f));
}

__global__ __launch_bounds__(256) void k_mp2_ls(
    const float* __restrict__ t1, const float* __restrict__ W,
    const float* __restrict__ b2, float* __restrict__ outp, int nrows) {
  int wid = (blockIdx.x * 256 + threadIdx.x) >> 6;
  int lane = threadIdx.x & 63;
  if (wid >= nrows) return;
  const float* row = t1 + (size_t)wid * DD;
  float x0 = row[lane], x1 = row[lane + 64];
  float p0 = x0 * W[lane] + x1 * W[lane + 64];
  float p1 = x0 * W[DD + lane] + x1 * W[DD + 64 + lane];
#pragma unroll
  for (int off = 32; off; off >>= 1) {
    p0 += __shfl_xor(p0, off);
    p1 += __shfl_xor(p1, off);
  }
  if (lane == 0) {
    float v0 = p0 + b2[0], v1 = p1 + b2[1];
    float m = fmaxf(v0, v1);
    float ls = m + logf(__expf(v0 - m) + __expf(v1 - m));
    outp[(size_t)wid * 2 + 0] = v0 - ls;
    outp[(size_t)wid * 2 + 1] = v1 - ls;
  }
}

__global__ void k_out(const float* __restrict__ stage, void* __restrict__ dout,
                      int n, const int* flag) {
  const int isf = flag[0];
  int i = blockIdx.x * 256 + threadIdx.x;
  if (i >= n) return;
  if (isf) ((float*)dout)[i] = stage[i];
  else ((u16*)dout)[i] = f2bf(stage[i]);
}

// ---------------------------------------------------------------- launch
extern "C" void kernel_launch(void* const* d_in, const int* in_sizes, int n_in,
                              void* d_out, int out_size, void* d_ws, size_t ws_size,
                              hipStream_t stream) {
  const int* idx_lp = (const int*)d_in[0];
  const int* len_lp = (const int*)d_in[1];
  const int* idx_ns = (const int*)d_in[2];
  const int* len_ns = (const int*)d_in[3];
  const void* x_ref = d_in[4];
  const void* x_def = d_in[5];
  const void* x_pdt = d_in[6];
  const int* eidx   = (const int*)d_in[7];
  const void* ew    = d_in[8];
  const void* lp_emb = d_in[9];

  // ---- workspace layout (~66 MB) ----
  int*   flag   = (int*)d_ws;                        // [16]
  float* base   = (float*)d_ws;
  float* smallW = base + 16;                         // 3088 f32
  float* f_xw   = base + 3104;                       // [N*128] f32
  float* f_agg  = f_xw + (size_t)NN * DD;            // [N*128] f32
  float* f_deg  = f_agg + (size_t)NN * DD;           // [N]
  float* f_dinv = f_deg + NN;                        // [N]
  float* stage  = f_dinv + NN;                       // [N*128 + 2N] f32
  u16* ub       = (u16*)(stage + (size_t)NN * DD + 2 * NN);
  // bf16 region offsets (u16 units)
  u16* embbf_lp = ub;                                //   640,000
  u16* embbf_ns = ub + 640000;                       // 1,280,000
  u16* wg_lpih  = ub + 1920000;                      //    49,152
  u16* wg_lphh  = ub + 1969152;
  u16* wg_nsih  = ub + 2018304;
  u16* wg_nshh  = ub + 2067456;
  u16* wg_lpfc  = ub + 2116608;                      //    49,152
  u16* wg_allfc = ub + 2165760;                      //    81,920
  u16* wg_c1    = ub + 2247680;                      //    16,384
  u16* wg_c2    = ub + 2264064;
  u16* wg_c3    = ub + 2280448;
  u16* wg_mp1   = ub + 2296832;
  u16* hbf_lp   = ub + 2313216;                      // 7,680,000 [3N,128]
  u16* hbf_ns   = ub + 9993216;                      // 2,560,000
  u16* lp_bf    = ub + 12553216;                     // 2,560,000
  u16* xcur_bf  = ub + 15113216;                     // 2,560,000
  u16* relu_bf  = hbf_lp;  // hbf_lp dead after lp_fc; reuse for mp1 input

  // f32 small-tensor conversions (biases, LN params, mp2)
  static const int fn[16] = {384, 384, 384, 384, 128, 128, 128, 128,
                             128, 128, 128, 128, 128, 128, 256, 2};
  static const int fsrc[16] = {13, 14, 17, 18, 20, 22, 24, 26,
                               28, 29, 30, 31, 32, 34, 35, 36};
  CvtJobs jf;
  int foff[16];
  {
    int off = 0;
    for (int j = 0; j < 16; ++j) {
      jf.src[j] = d_in[fsrc[j]];
      jf.off[j] = off;
      jf.n[j] = fn[j];
      foff[j] = off;
      off += fn[j];
    }
  }
  float* b_lpbih = smallW + foff[0];
  float* b_lpbhh = smallW + foff[1];
  float* b_nsbih = smallW + foff[2];
  float* b_nsbhh = smallW + foff[3];
  float* b_lpfc  = smallW + foff[4];
  float* b_allfc = smallW + foff[5];
  float* b_conv[3] = {smallW + foff[6], smallW + foff[7], smallW + foff[8]};
  float* g_ln[2] = {smallW + foff[9], smallW + foff[11]};
  float* b_ln[2] = {smallW + foff[10], smallW + foff[12]};
  float* b_mp1   = smallW + foff[13];
  float* w_mp2   = smallW + foff[14];
  float* b_mp2   = smallW + foff[15];

  // bf16 conversions (embeddings + all MFMA weights)
  static const int bn[12] = {640000, 1280000, 49152, 49152, 49152, 49152,
                             49152, 81920, 16384, 16384, 16384, 16384};
  static const int bsrc[12] = {9, 10, 11, 12, 15, 16, 19, 21, 23, 25, 27, 33};
  static const int boff[12] = {0, 640000, 1920000, 1969152, 2018304, 2067456,
                               2116608, 2165760, 2247680, 2264064, 2280448,
                               2296832};
  CvtJobsB jb;
  for (int j = 0; j < 12; ++j) {
    jb.src[j] = d_in[bsrc[j]];
    jb.off[j] = boff[j];
    jb.n[j] = bn[j];
  }

  const int* e_src = eidx;
  const int* e_dst = eidx + EE;

  // 0. dtype detection
  k_detect<<<1, 256, 0, stream>>>(lp_emb, flag);

  // 1. conversions
  k_cvt_batch<<<16, 256, 0, stream>>>(jf, smallW, flag);
  k_cvtb<<<12 * 64, 256, 0, stream>>>(jb, ub, flag);

  // 2. GRUs (LP: slot sg=p*N+i reads row i*P+p -> flat [P,N,D] bf16 output)
  k_gru2<<<PP * NN / 32, 256, 0, stream>>>(embbf_lp, idx_lp, len_lp, wg_lpih,
                                           wg_lphh, b_lpbih, b_lpbhh, hbf_lp,
                                           PP * NN, TLP, 0, NN);
  k_gru2<<<NN / 32, 256, 0, stream>>>(embbf_ns, idx_ns, len_ns, wg_nsih,
                                      wg_nshh, b_nsbih, b_nsbhh, hbf_ns,
                                      NN, TNS, 1, NN);

  const int gg = (NN + 63) / 64;  // 313 blocks
  // 3. lp_fc: hbf_lp flat [3N,128] viewed [N,384] == faithful reshape
  k_gemm_mfma<<<gg, 256, 0, stream>>>(hbf_lp, nullptr, nullptr, nullptr, nullptr,
                                      0, 384, wg_lpfc, b_lpfc, lp_bf, 1, NN, flag);
  // 4. all_fc: scramble-gather {pdt, ref, def, lp, ns} -> xcur_bf
  k_gemm_mfma<<<gg, 256, 0, stream>>>(x_pdt, x_ref, x_def, lp_bf, hbf_ns,
                                      1, 640, wg_allfc, b_allfc, xcur_bf, 1, NN, flag);

  // 5. degrees
  k_deg_init<<<(NN + 255) / 256, 256, 0, stream>>>(f_deg, NN);
  k_deg_acc<<<(EE + 255) / 256, 256, 0, stream>>>(e_dst, ew, f_deg, EE, flag);
  k_dinv<<<(NN + 255) / 256, 256, 0, stream>>>(f_deg, f_dinv, NN);

  // 6. three GCN layers
  const u16* wgc[3] = {wg_c1, wg_c2, wg_c3};
  int cg = (NN * DD + 255) / 256;
  for (int l = 0; l < 3; ++l) {
    k_gemm_mfma<<<gg, 256, 0, stream>>>(xcur_bf, nullptr, nullptr, nullptr, nullptr,
                                        0, DD, wgc[l], nullptr, f_xw, 0, NN, flag);
    k_gcn_self<<<cg, 256, 0, stream>>>(f_xw, f_dinv, b_conv[l], f_agg, NN * DD);
    k_gcn_edges<<<EE / 2, 256, 0, stream>>>(e_src, e_dst, ew, f_dinv, f_xw, f_agg,
                                            EE, flag);
    if (l < 2) {
      k_relu_ln<<<(NN + 3) / 4, 256, 0, stream>>>(f_agg, g_ln[l], b_ln[l], xcur_bf, NN);
    } else {
      k_emb_relu<<<cg, 256, 0, stream>>>(f_agg, stage, relu_bf, NN * DD);
    }
  }

  // 7. mp head (no activation between mp1/mp2) + log_softmax
  k_gemm_mfma<<<gg, 256, 0, stream>>>(relu_bf, nullptr, nullptr, nullptr, nullptr,
                                      0, DD, wg_mp1, b_mp1, f_xw, 0, NN, flag);
  k_mp2_ls<<<(NN + 3) / 4, 256, 0, stream>>>(f_xw, w_mp2, b_mp2,
                                             stage + (size_t)NN * DD, NN);

  // 8. store in detected output dtype
  k_out<<<(out_size + 255) / 256, 256, 0, stream>>>(stage, d_out, out_size, flag);
}

// Round 6
// 1296.117 us; speedup vs baseline: 6.4420x; 1.3982x over previous
//
#include <hip/hip_runtime.h>
#include <math.h>

typedef unsigned short u16;
typedef short bf16x8 __attribute__((ext_vector_type(8)));
typedef float f32x16 __attribute__((ext_vector_type(16)));

#define NN 20000
#define PP 3
#define TLP 10
#define TNS 20
#define DD 128
#define EE 640000

__device__ __forceinline__ float bf2f(u16 u) {
  union { unsigned u; float f; } v; v.u = ((unsigned)u) << 16; return v.f;
}
__device__ __forceinline__ u16 f2bf(float f) {
  union { float f; unsigned u; } v; v.f = f;
  unsigned r = v.u + 0x7fffu + ((v.u >> 16) & 1u);
  return (u16)(r >> 16);
}
__device__ __forceinline__ float fsig(float x) {
  return __fdividef(1.f, 1.f + __expf(-x));
}
__device__ __forceinline__ float ftanh(float x) {
  float t = __expf(-2.f * fabsf(x));
  float r = __fdividef(1.f - t, 1.f + t);
  return copysignf(r, x);
}
__device__ __forceinline__ float loadf(const void* p, size_t i, int isf) {
  return isf ? ((const float*)p)[i] : bf2f(((const u16*)p)[i]);
}

// ------------------------------------------------------------- dtype detect
__global__ void k_detect(const void* probe, int* flag) {
  __shared__ int any;
  if (threadIdx.x == 0) any = 0;
  __syncthreads();
  const u16* p = (const u16*)probe;
  int bad = 0;
  for (int i = threadIdx.x; i < 4096; i += 256) {
    int e = (p[2 * i] >> 7) & 0xFF;
    if (e >= 0x9F) bad = 1;
  }
  if (bad) atomicOr(&any, 1);
  __syncthreads();
  if (threadIdx.x == 0) flag[0] = any;  // 1 = f32, 0 = bf16
}

// ------------------------------------------------------------- converters
struct CvtJobs {
  const void* src[16];
  int off[16];
  int n[16];
};

__global__ void k_cvt_batch(CvtJobs jobs, float* dst, const int* flag) {
  const int isf = flag[0];
  const void* s = jobs.src[blockIdx.x];
  float* d = dst + jobs.off[blockIdx.x];
  const int n = jobs.n[blockIdx.x];
  for (int i = threadIdx.x; i < n; i += 256) d[i] = loadf(s, i, isf);
}

struct CvtJobsB {
  const void* src[12];
  int off[12];
  int n[12];
};

__global__ void k_cvtb(CvtJobsB j, u16* __restrict__ dst, const int* flag) {
  const int isf = flag[0];
  const int job = blockIdx.x >> 6;
  const int chunk = blockIdx.x & 63;
  const void* s = j.src[job];
  u16* d = dst + j.off[job];
  const int n = j.n[job];
  for (int i = chunk * 256 + threadIdx.x; i < n; i += 64 * 256)
    d[i] = f2bf(loadf(s, i, isf));
}

// ---------------------------------------------------------------- GRU (wave-specialized MFMA)
// 512 thr = 8 waves, 32 seqs/block. Waves 0-3: X-producers (Wih frags only),
// write X-preacts into 2-slot LDS ring. Waves 4-7: H-consumers (Whh frags),
// run the recurrence, h state f32 in C-layout regs, Hbf double-buffered.
// One barrier per step. Per-wave regs ~230 -> 2 waves/SIMD.
__global__ __launch_bounds__(512, 2) void k_gru3(
    const u16* __restrict__ embbf,   // [V,128] bf16
    const int* __restrict__ idx,     // [rows,T]
    const int* __restrict__ lens,    // [rows]
    const u16* __restrict__ Wih,     // [384][128] bf16
    const u16* __restrict__ Whh,     // [384][128] bf16
    const float* __restrict__ bih,   // [384] f32
    const float* __restrict__ bhh,   // [384] f32
    u16* __restrict__ Houtbf,        // [numSeq,128] bf16
    int numSeq, int T, int mode, int Nn) {
  __shared__ float xp[2][3][4][32][33];  // [slot][gate][chunk][col][m], pad 33
  __shared__ u16 Hbf[2][4096];           // A-frag order ((k>>3)*32+m)*8+(k&7)
  __shared__ int ivs[TNS][32];
  __shared__ int rowv[32], lenv_s[32];

  const int tid = threadIdx.x;
  const int w = tid >> 6, lane = tid & 63;
  const int l31 = lane & 31, lh = lane >> 5;
  const int role = w >> 2;  // 0 = X producer, 1 = H consumer
  const int j = w & 3;
  const int d = 32 * j + l31;

  if (tid < 32) {
    int sg = blockIdx.x * 32 + tid;
    int row = (mode == 0) ? ((sg % Nn) * PP + sg / Nn) : sg;
    rowv[tid] = row;
    lenv_s[tid] = lens[row];
  }
  __syncthreads();
  for (int z = tid; z < T * 32; z += 512) {
    int s = z & 31, t = z >> 5;
    ivs[t][s] = idx[(size_t)rowv[s] * T + t];
  }
  ((bf16x8*)Hbf[0])[tid] = (bf16x8)(short)0;  // 512 x 16B = 8KB slot 0

  // weight frags: X-waves hold Wih cols [32j,32j+32) x 3 gates; H-waves Whh.
  bf16x8 wf[24];
  {
    const u16* Ws = role ? Whh : Wih;
#pragma unroll
    for (int g = 0; g < 3; ++g)
#pragma unroll
      for (int kb = 0; kb < 8; ++kb)
        wf[g * 8 + kb] =
            *(const bf16x8*)(Ws + (size_t)(128 * g + d) * 128 + kb * 16 + lh * 8);
  }
  const float bsr = bih[d] + bhh[d];
  const float bsz = bih[128 + d] + bhh[128 + d];
  const float bin = bih[256 + d];
  const float bhn = bhh[256 + d];

  __syncthreads();
  int lenr[16];
#pragma unroll
  for (int rg = 0; rg < 16; ++rg)
    lenr[rg] = lenv_s[(rg & 3) + 8 * (rg >> 2) + 4 * lh];

  float h[16];
#pragma unroll
  for (int rg = 0; rg < 16; ++rg) h[rg] = 0.f;

  for (int i = 0; i <= T; ++i) {
    if (!role) {
      if (i < T) {  // produce xp(i) into slot i&1
        bf16x8 Xf[8];
        const u16* erow = embbf + (size_t)ivs[i][l31] * 128 + lh * 8;
#pragma unroll
        for (int kb = 0; kb < 8; ++kb) Xf[kb] = *(const bf16x8*)(erow + kb * 16);
        f32x16 a0 = (f32x16)(0.f), a1 = (f32x16)(0.f), a2 = (f32x16)(0.f);
#pragma unroll
        for (int kb = 0; kb < 8; ++kb) {
          a0 = __builtin_amdgcn_mfma_f32_32x32x16_bf16(Xf[kb], wf[kb], a0, 0, 0, 0);
          a1 = __builtin_amdgcn_mfma_f32_32x32x16_bf16(Xf[kb], wf[8 + kb], a1, 0, 0, 0);
          a2 = __builtin_amdgcn_mfma_f32_32x32x16_bf16(Xf[kb], wf[16 + kb], a2, 0, 0, 0);
        }
        const int sl = i & 1;
#pragma unroll
        for (int rg = 0; rg < 16; ++rg) {
          int m = (rg & 3) + 8 * (rg >> 2) + 4 * lh;
          xp[sl][0][j][l31][m] = a0[rg];
          xp[sl][1][j][l31][m] = a1[rg];
          xp[sl][2][j][l31][m] = a2[rg];
        }
      }
    } else {
      if (i >= 1) {  // consume xp(i-1), h(i-2) -> h(i-1)
        const int rs = (i - 1) & 1, wsl = i & 1;
        bf16x8 Hf[8];
#pragma unroll
        for (int kb = 0; kb < 8; ++kb)
          Hf[kb] = *(const bf16x8*)(Hbf[rs] + (2 * kb + lh) * 256 + l31 * 8);
        f32x16 a0 = (f32x16)(0.f), a1 = (f32x16)(0.f), a2 = (f32x16)(0.f);
#pragma unroll
        for (int kb = 0; kb < 8; ++kb) {
          a0 = __builtin_amdgcn_mfma_f32_32x32x16_bf16(Hf[kb], wf[kb], a0, 0, 0, 0);
          a1 = __builtin_amdgcn_mfma_f32_32x32x16_bf16(Hf[kb], wf[8 + kb], a1, 0, 0, 0);
          a2 = __builtin_amdgcn_mfma_f32_32x32x16_bf16(Hf[kb], wf[16 + kb], a2, 0, 0, 0);
        }
        const int t = i - 1;
#pragma unroll
        for (int rg = 0; rg < 16; ++rg) {
          int m = (rg & 3) + 8 * (rg >> 2) + 4 * lh;
          float r = fsig(a0[rg] + xp[rs][0][j][l31][m] + bsr);
          float z = fsig(a1[rg] + xp[rs][1][j][l31][m] + bsz);
          float nn_ = ftanh(xp[rs][2][j][l31][m] + bin + r * (a2[rg] + bhn));
          float hnew = (1.f - z) * nn_ + z * h[rg];
          h[rg] = (t < lenr[rg]) ? hnew : h[rg];  // pack_padded mask
          Hbf[wsl][((d >> 3) * 32 + m) * 8 + (d & 7)] = f2bf(h[rg]);
        }
      }
    }
    __syncthreads();
  }

  if (role) {
    const int sgb = blockIdx.x * 32;
#pragma unroll
    for (int rg = 0; rg < 16; ++rg) {
      int m = (rg & 3) + 8 * (rg >> 2) + 4 * lh;
      Houtbf[(size_t)(sgb + m) * 128 + d] = f2bf(h[rg]);
    }
  }
}

// ---------------------------------------------------------------- GEMM (MFMA, LDS-free)
__global__ __launch_bounds__(256) void k_gemm_mfma(
    const void* __restrict__ A0, const void* __restrict__ A1,
    const void* __restrict__ A2, const u16* __restrict__ A3,
    const u16* __restrict__ A4, int mode, int K,
    const u16* __restrict__ W, const float* __restrict__ bias,
    void* __restrict__ Cout, int out_bf, int M, const int* __restrict__ flag) {
  const int isf = flag[0];
  const int tid = threadIdx.x;
  const int w = tid >> 6, lane = tid & 63;
  const int l31 = lane & 31, lh = lane >> 5;
  const int w01 = w & 1, w23 = w >> 1;
  const int mbase = blockIdx.x * 64 + 32 * w01;
  const int row = mbase + l31;
  const int rowc = row < M ? row : M - 1;

  f32x16 acc0 = (f32x16)(0.f), acc1 = (f32x16)(0.f);
  const int nk = K >> 4;
  for (int kb = 0; kb < nk; ++kb) {
    bf16x8 a;
    if (mode == 0) {
      a = *(const bf16x8*)((const u16*)A0 + (size_t)rowc * K + kb * 16 + lh * 8);
    } else {
      int r5 = 5 * rowc + (kb >> 3);
      int slot = r5 / NN;
      int inner = r5 - slot * NN;
      int koff = (kb & 7) * 16 + lh * 8;
      if (slot < 3) {
        const void* p = (slot == 0) ? A0 : (slot == 1) ? A1 : A2;
        if (isf) {
          const float* fp = (const float*)p + (size_t)inner * 128 + koff;
          float4 v0 = *(const float4*)fp;
          float4 v1 = *(const float4*)(fp + 4);
          a[0] = (short)f2bf(v0.x); a[1] = (short)f2bf(v0.y);
          a[2] = (short)f2bf(v0.z); a[3] = (short)f2bf(v0.w);
          a[4] = (short)f2bf(v1.x); a[5] = (short)f2bf(v1.y);
          a[6] = (short)f2bf(v1.z); a[7] = (short)f2bf(v1.w);
        } else {
          a = *(const bf16x8*)((const u16*)p + (size_t)inner * 128 + koff);
        }
      } else {
        const u16* p = (slot == 3) ? A3 : A4;
        a = *(const bf16x8*)(p + (size_t)inner * 128 + koff);
      }
    }
    const u16* wp = W + (size_t)(64 * w23 + l31) * K + kb * 16 + lh * 8;
    bf16x8 b0 = *(const bf16x8*)wp;
    bf16x8 b1 = *(const bf16x8*)(wp + (size_t)32 * K);
    acc0 = __builtin_amdgcn_mfma_f32_32x32x16_bf16(a, b0, acc0, 0, 0, 0);
    acc1 = __builtin_amdgcn_mfma_f32_32x32x16_bf16(a, b1, acc1, 0, 0, 0);
  }
  const int col0 = 64 * w23 + l31;
  const float bv0 = bias ? bias[col0] : 0.f;
  const float bv1 = bias ? bias[col0 + 32] : 0.f;
#pragma unroll
  for (int rg = 0; rg < 16; ++rg) {
    int m = (rg & 3) + 8 * (rg >> 2) + 4 * lh;
    int grow = mbase + m;
    if (grow < M) {
      float v0 = acc0[rg] + bv0, v1 = acc1[rg] + bv1;
      if (out_bf) {
        ((u16*)Cout)[(size_t)grow * 128 + col0] = f2bf(v0);
        ((u16*)Cout)[(size_t)grow * 128 + col0 + 32] = f2bf(v1);
      } else {
        ((float*)Cout)[(size_t)grow * 128 + col0] = v0;
        ((float*)Cout)[(size_t)grow * 128 + col0 + 32] = v1;
      }
    }
  }
}

// ---------------------------------------------------------------- CSR build
__global__ void k_zero_i(int* __restrict__ p, int n) {
  int i = blockIdx.x * 256 + threadIdx.x;
  if (i < n) p[i] = 0;
}

__global__ void k_hist(const int* __restrict__ dst, int* __restrict__ counts, int E) {
  int e = blockIdx.x * 256 + threadIdx.x;
  if (e < E) atomicAdd(&counts[dst[e]], 1);
}

__global__ void k_scan(const int* __restrict__ counts, int* __restrict__ start,
                       int* __restrict__ cursor, int n) {
  __shared__ int part[256];
  const int C = (n + 255) / 256;
  int tid = threadIdx.x;
  int base = tid * C;
  int s = 0;
  for (int k = 0; k < C; ++k) {
    int i = base + k;
    s += (i < n) ? counts[i] : 0;
  }
  part[tid] = s;
  __syncthreads();
  if (tid == 0) {
    int acc = 0;
    for (int k = 0; k < 256; ++k) { int v = part[k]; part[k] = acc; acc += v; }
  }
  __syncthreads();
  int run = part[tid];
  for (int k = 0; k < C; ++k) {
    int i = base + k;
    if (i < n) {
      int c = counts[i];
      start[i] = run;
      cursor[i] = run;
      run += c;
    }
  }
  if (tid == 255) start[n] = run;
}

__global__ void k_fill(const int* __restrict__ dst, int* __restrict__ cursor,
                       int* __restrict__ order, int E) {
  int e = blockIdx.x * 256 + threadIdx.x;
  if (e < E) {
    int p = atomicAdd(&cursor[dst[e]], 1);
    order[p] = e;
  }
}

// ---------------------------------------------------------------- degrees
__global__ void k_deg_init(float* __restrict__ deg, int n) {
  int i = blockIdx.x * 256 + threadIdx.x;
  if (i < n) deg[i] = 1.f;
}

__global__ void k_deg_acc(const int* __restrict__ dst, const void* __restrict__ w,
                          float* __restrict__ deg, int E, const int* flag) {
  const int isf = flag[0];
  int e = blockIdx.x * 256 + threadIdx.x;
  if (e < E) atomicAdd(&deg[dst[e]], loadf(w, e, isf));
}

__global__ void k_dinv(const float* __restrict__ deg, float* __restrict__ dinv, int n) {
  int i = blockIdx.x * 256 + threadIdx.x;
  if (i < n) dinv[i] = 1.f / sqrtf(deg[i]);
}

// ------------------------------------------------- fused GCN gather epilogue
// 1 wave per dst node; CSR gather (no atomics) + self-loop + bias, then
// mode 0: ReLU+LayerNorm -> bf16; mode 1: emb f32 + ReLU bf16.
__global__ __launch_bounds__(256) void k_gcn_gather(
    const int* __restrict__ start, const int* __restrict__ order,
    const int* __restrict__ esrc, const void* __restrict__ ew,
    const float* __restrict__ dinv, const float* __restrict__ xw,
    const float* __restrict__ bias, const float* __restrict__ g,
    const float* __restrict__ b, u16* __restrict__ out_bf,
    float* __restrict__ emb_out, int mode, const int* __restrict__ flag) {
  const int isf = flag[0];
  int v = blockIdx.x * 4 + (threadIdx.x >> 6);
  int lane = threadIdx.x & 63;
  if (v >= NN) return;
  float acc0 = 0.f, acc1 = 0.f;
  const int i1 = start[v + 1];
  for (int i = start[v]; i < i1; ++i) {
    int e = order[i];
    int s = esrc[e];
    float c = dinv[s] * loadf(ew, e, isf);
    acc0 += c * xw[(size_t)s * 128 + lane];
    acc1 += c * xw[(size_t)s * 128 + 64 + lane];
  }
  float dv = dinv[v];
  float y0 = bias[lane] + dv * (dv * xw[(size_t)v * 128 + lane] + acc0);
  float y1 = bias[64 + lane] + dv * (dv * xw[(size_t)v * 128 + 64 + lane] + acc1);
  if (mode == 1) {
    emb_out[(size_t)v * 128 + lane] = y0;
    emb_out[(size_t)v * 128 + 64 + lane] = y1;
    out_bf[(size_t)v * 128 + lane] = f2bf(fmaxf(y0, 0.f));
    out_bf[(size_t)v * 128 + 64 + lane] = f2bf(fmaxf(y1, 0.f));
  } else {
    float x0 = fmaxf(y0, 0.f), x1 = fmaxf(y1, 0.f);
    float s_ = x0 + x1;
#pragma unroll
    for (int off = 32; off; off >>= 1) s_ += __shfl_xor(s_, off);
    float mean = s_ * (1.f / 128.f);
    float e0 = x0 - mean, e1 = x1 - mean;
    float vv = e0 * e0 + e1 * e1;
#pragma unroll
    for (int off = 32; off; off >>= 1) vv += __shfl_xor(vv, off);
    float inv = 1.f / sqrtf(vv * (1.f / 128.f) + 1e-5f);
    out_bf[(size_t)v * 128 + lane] = f2bf(e0 * inv * g[lane] + b[lane]);
    out_bf[(size_t)v * 128 + 64 + lane] =
        f2bf(e1 * inv * g[64 + lane] + b[64 + lane]);
  }
}

// ---------------------------------------------------------------- head
__global__ __launch_bounds__(256) void k_mp2_ls(
    const float* __restrict__ t1, const float* __restrict__ W,
    const float* __restrict__ b2, float* __restrict__ outp, int nrows) {
  int wid = (blockIdx.x * 256 + threadIdx.x) >> 6;
  int lane = threadIdx.x & 63;
  if (wid >= nrows) return;
  const float* row = t1 + (size_t)wid * DD;
  float x0 = row[lane], x1 = row[lane + 64];
  float p0 = x0 * W[lane] + x1 * W[lane + 64];
  float p1 = x0 * W[DD + lane] + x1 * W[DD + 64 + lane];
#pragma unroll
  for (int off = 32; off; off >>= 1) {
    p0 += __shfl_xor(p0, off);
    p1 += __shfl_xor(p1, off);
  }
  if (lane == 0) {
    float v0 = p0 + b2[0], v1 = p1 + b2[1];
    float m = fmaxf(v0, v1);
    float ls = m + logf(__expf(v0 - m) + __expf(v1 - m));
    outp[(size_t)wid * 2 + 0] = v0 - ls;
    outp[(size_t)wid * 2 + 1] = v1 - ls;
  }
}

__global__ void k_out(const float* __restrict__ stage, void* __restrict__ dout,
                      int n, const int* flag) {
  const int isf = flag[0];
  int i = blockIdx.x * 256 + threadIdx.x;
  if (i >= n) return;
  if (isf) ((float*)dout)[i] = stage[i];
  else ((u16*)dout)[i] = f2bf(stage[i]);
}

// ---------------------------------------------------------------- launch
extern "C" void kernel_launch(void* const* d_in, const int* in_sizes, int n_in,
                              void* d_out, int out_size, void* d_ws, size_t ws_size,
                              hipStream_t stream) {
  const int* idx_lp = (const int*)d_in[0];
  const int* len_lp = (const int*)d_in[1];
  const int* idx_ns = (const int*)d_in[2];
  const int* len_ns = (const int*)d_in[3];
  const void* x_ref = d_in[4];
  const void* x_def = d_in[5];
  const void* x_pdt = d_in[6];
  const int* eidx   = (const int*)d_in[7];
  const void* ew    = d_in[8];
  const void* lp_emb = d_in[9];

  // ---- workspace layout (~59 MB) ----
  int*   flag   = (int*)d_ws;
  float* base   = (float*)d_ws;
  float* smallW = base + 16;                         // 3088 f32
  float* f_xw   = base + 3104;                       // [N*128]
  float* f_deg  = f_xw + (size_t)NN * DD;            // [N]
  float* f_dinv = f_deg + NN;                        // [N]
  float* stage  = f_dinv + NN;                       // [N*128 + 2N]
  int* counts   = (int*)(stage + (size_t)NN * DD + 2 * NN);  // [N]
  int* startA   = counts + NN;                       // [N+1]
  int* cursor   = startA + NN + 1;                   // [N]
  int* order    = cursor + NN;                       // [E]
  u16* ub       = (u16*)(((char*)(order + EE)) + 64);  // aligned bf16 region
  u16* embbf_lp = ub;                                //   640,000
  u16* embbf_ns = ub + 640000;                       // 1,280,000
  u16* wg_lpih  = ub + 1920000;
  u16* wg_lphh  = ub + 1969152;
  u16* wg_nsih  = ub + 2018304;
  u16* wg_nshh  = ub + 2067456;
  u16* wg_lpfc  = ub + 2116608;
  u16* wg_allfc = ub + 2165760;
  u16* wg_c1    = ub + 2247680;
  u16* wg_c2    = ub + 2264064;
  u16* wg_c3    = ub + 2280448;
  u16* wg_mp1   = ub + 2296832;
  u16* hbf_lp   = ub + 2313216;                      // [3N,128]
  u16* hbf_ns   = ub + 9993216;                      // [N,128]
  u16* lp_bf    = ub + 12553216;                     // [N,128]
  u16* xcur_bf  = ub + 15113216;                     // [N,128]
  u16* relu_bf  = hbf_lp;  // dead after lp_fc

  static const int fn[16] = {384, 384, 384, 384, 128, 128, 128, 128,
                             128, 128, 128, 128, 128, 128, 256, 2};
  static const int fsrc[16] = {13, 14, 17, 18, 20, 22, 24, 26,
                               28, 29, 30, 31, 32, 34, 35, 36};
  CvtJobs jf;
  int foff[16];
  {
    int off = 0;
    for (int j = 0; j < 16; ++j) {
      jf.src[j] = d_in[fsrc[j]];
      jf.off[j] = off;
      jf.n[j] = fn[j];
      foff[j] = off;
      off += fn[j];
    }
  }
  float* b_lpbih = smallW + foff[0];
  float* b_lpbhh = smallW + foff[1];
  float* b_nsbih = smallW + foff[2];
  float* b_nsbhh = smallW + foff[3];
  float* b_lpfc  = smallW + foff[4];
  float* b_allfc = smallW + foff[5];
  float* b_conv[3] = {smallW + foff[6], smallW + foff[7], smallW + foff[8]};
  float* g_ln[2] = {smallW + foff[9], smallW + foff[11]};
  float* b_ln[2] = {smallW + foff[10], smallW + foff[12]};
  float* b_mp1   = smallW + foff[13];
  float* w_mp2   = smallW + foff[14];
  float* b_mp2   = smallW + foff[15];

  static const int bn[12] = {640000, 1280000, 49152, 49152, 49152, 49152,
                             49152, 81920, 16384, 16384, 16384, 16384};
  static const int bsrc[12] = {9, 10, 11, 12, 15, 16, 19, 21, 23, 25, 27, 33};
  static const int boff[12] = {0, 640000, 1920000, 1969152, 2018304, 2067456,
                               2116608, 2165760, 2247680, 2264064, 2280448,
                               2296832};
  CvtJobsB jb;
  for (int j = 0; j < 12; ++j) {
    jb.src[j] = d_in[bsrc[j]];
    jb.off[j] = boff[j];
    jb.n[j] = bn[j];
  }

  const int* e_src = eidx;
  const int* e_dst = eidx + EE;

  // 0. dtype detection
  k_detect<<<1, 256, 0, stream>>>(lp_emb, flag);

  // 1. conversions
  k_cvt_batch<<<16, 256, 0, stream>>>(jf, smallW, flag);
  k_cvtb<<<12 * 64, 256, 0, stream>>>(jb, ub, flag);

  // 2. CSR build (used by all 3 conv layers) + degrees
  k_zero_i<<<(NN + 255) / 256, 256, 0, stream>>>(counts, NN);
  k_hist<<<(EE + 255) / 256, 256, 0, stream>>>(e_dst, counts, EE);
  k_scan<<<1, 256, 0, stream>>>(counts, startA, cursor, NN);
  k_fill<<<(EE + 255) / 256, 256, 0, stream>>>(e_dst, cursor, order, EE);
  k_deg_init<<<(NN + 255) / 256, 256, 0, stream>>>(f_deg, NN);
  k_deg_acc<<<(EE + 255) / 256, 256, 0, stream>>>(e_dst, ew, f_deg, EE, flag);
  k_dinv<<<(NN + 255) / 256, 256, 0, stream>>>(f_deg, f_dinv, NN);

  // 3. GRUs (wave-specialized; LP slot sg=p*N+i reads row i*P+p -> [P,N,D])
  k_gru3<<<PP * NN / 32, 512, 0, stream>>>(embbf_lp, idx_lp, len_lp, wg_lpih,
                                           wg_lphh, b_lpbih, b_lpbhh, hbf_lp,
                                           PP * NN, TLP, 0, NN);
  k_gru3<<<NN / 32, 512, 0, stream>>>(embbf_ns, idx_ns, len_ns, wg_nsih,
                                      wg_nshh, b_nsbih, b_nsbhh, hbf_ns,
                                      NN, TNS, 1, NN);

  const int gg = (NN + 63) / 64;
  // 4. lp_fc: hbf_lp flat [3N,128] viewed [N,384] == faithful reshape
  k_gemm_mfma<<<gg, 256, 0, stream>>>(hbf_lp, nullptr, nullptr, nullptr, nullptr,
                                      0, 384, wg_lpfc, b_lpfc, lp_bf, 1, NN, flag);
  // 5. all_fc: scramble-gather {pdt, ref, def, lp, ns} -> xcur_bf
  k_gemm_mfma<<<gg, 256, 0, stream>>>(x_pdt, x_ref, x_def, lp_bf, hbf_ns,
                                      1, 640, wg_allfc, b_allfc, xcur_bf, 1, NN, flag);

  // 6. three GCN layers: GEMM + fused CSR gather/self/bias/ReLU/LN
  const u16* wgc[3] = {wg_c1, wg_c2, wg_c3};
  for (int l = 0; l < 3; ++l) {
    k_gemm_mfma<<<gg, 256, 0, stream>>>(xcur_bf, nullptr, nullptr, nullptr, nullptr,
                                        0, DD, wgc[l], nullptr, f_xw, 0, NN, flag);
    if (l < 2) {
      k_gcn_gather<<<NN / 4, 256, 0, stream>>>(startA, order, e_src, ew, f_dinv,
                                               f_xw, b_conv[l], g_ln[l], b_ln[l],
                                               xcur_bf, nullptr, 0, flag);
    } else {
      k_gcn_gather<<<NN / 4, 256, 0, stream>>>(startA, order, e_src, ew, f_dinv,
                                               f_xw, b_conv[l], nullptr, nullptr,
                                               relu_bf, stage, 1, flag);
    }
  }

  // 7. mp head (no activation between mp1/mp2) + log_softmax
  k_gemm_mfma<<<gg, 256, 0, stream>>>(relu_bf, nullptr, nullptr, nullptr, nullptr,
                                      0, DD, wg_mp1, b_mp1, f_xw, 0, NN, flag);
  k_mp2_ls<<<(NN + 3) / 4, 256, 0, stream>>>(f_xw, w_mp2, b_mp2,
                                             stage + (size_t)NN * DD, NN);

  // 8. store in detected output dtype
  k_out<<<(out_size + 255) / 256, 256, 0, stream>>>(stage, d_out, out_size, flag);
}